// Round 1
// baseline (1247.640 us; speedup 1.0000x reference)
//
#include <hip/hip_runtime.h>
#include <math.h>

#define LSEQ   1080
#define NBATCH 16
#define BLROWS (LSEQ*NBATCH)   // 17280
#define CHN    27
#define LCH    40              // 27*40 = 1080

__device__ __forceinline__ float silu_f(float x) { return x / (1.f + __expf(-x)); }

// ---------------- embed + positional encoding ----------------
__global__ __launch_bounds__(256) void embed_kernel(
    const float* __restrict__ x, const float* __restrict__ embW,
    const float* __restrict__ embb, float* __restrict__ xe)
{
    int idx = blockIdx.x * 256 + threadIdx.x;
    if (idx >= BLROWS * 128) return;
    int d = idx & 127;
    int r = idx >> 7;
    int t = r % LSEQ;
    float x0 = x[(size_t)r * 2], x1 = x[(size_t)r * 2 + 1];
    int i2 = d & 126;
    float div = expf((float)i2 * (-9.210340371976184f / 128.f));
    float arg = (float)t * div;
    float pe = (d & 1) ? cosf(arg) : sinf(arg);
    xe[idx] = fmaf(x0, embW[d], fmaf(x1, embW[128 + d], embb[d] + pe));
}

// ---------------- generic tiled fp32 GEMM with conv taps + epilogues ----------
// C[b, t, n] = epi( sum_{tap, d} A[b, t+tap-pad, d] * W[n, d, tap] )
// W element index: n*wsn + d*KT + tap   (KT==1 -> plain n*wsn + d)
template<int RM, int RN>
__global__ __launch_bounds__(256) void gemm_kernel(
    const float* __restrict__ A, int lda,
    const float* __restrict__ W, int wsn,
    int Ntot, int Kd, int KT, int pad,
    const float* __restrict__ bias,
    const float* __restrict__ bn, int bnN,
    int epi,
    float* __restrict__ C, int ldc)
{
    constexpr int BM = 16 * RM, BN = 16 * RN;
    __shared__ float As[16][BM + 4];
    __shared__ float Ws[16][BN + 4];
    const int tid = threadIdx.x;
    const int b  = blockIdx.z;
    const int t0 = blockIdx.y * BM;
    const int n0 = blockIdx.x * BN;
    const float* Ab = A + (size_t)b * LSEQ * lda;
    float acc[RM][RN];
#pragma unroll
    for (int i = 0; i < RM; ++i)
#pragma unroll
        for (int j = 0; j < RN; ++j) acc[i][j] = 0.f;
    const int tx = tid & 15, ty = tid >> 4;
    const int K16 = Kd >> 4;
    for (int tap = 0; tap < KT; ++tap) {
        const int shift = tap - pad;
        for (int dc = 0; dc < K16; ++dc) {
            // A tile: BM rows x 16 k
#pragma unroll
            for (int l = 0; l < (BM * 16) / 1024; ++l) {
                int vid = tid + l * 256;
                int row = vid >> 2;
                int kq  = (vid & 3) << 2;
                int t = t0 + row;
                int ts = t + shift;
                float4 av = make_float4(0.f, 0.f, 0.f, 0.f);
                if (t < LSEQ && ts >= 0 && ts < LSEQ)
                    av = *(const float4*)(Ab + (size_t)ts * lda + dc * 16 + kq);
                As[kq + 0][row] = av.x; As[kq + 1][row] = av.y;
                As[kq + 2][row] = av.z; As[kq + 3][row] = av.w;
            }
            // W tile: BN rows x 16 k
#pragma unroll
            for (int l = 0; l < (BN * 16) / 1024; ++l) {
                int vid = tid + l * 256;
                int wn = vid >> 2;
                int kq = (vid & 3) << 2;
                int n = n0 + wn;
                float4 wv = make_float4(0.f, 0.f, 0.f, 0.f);
                if (n < Ntot) {
                    if (KT == 1) {
                        wv = *(const float4*)(W + (size_t)n * wsn + dc * 16 + kq);
                    } else {
                        const float* wp = W + (size_t)n * wsn + (size_t)(dc * 16 + kq) * KT + tap;
                        wv.x = wp[0]; wv.y = wp[KT]; wv.z = wp[2 * KT]; wv.w = wp[3 * KT];
                    }
                }
                Ws[kq + 0][wn] = wv.x; Ws[kq + 1][wn] = wv.y;
                Ws[kq + 2][wn] = wv.z; Ws[kq + 3][wn] = wv.w;
            }
            __syncthreads();
#pragma unroll
            for (int kk = 0; kk < 16; ++kk) {
                float af[RM], bf[RN];
#pragma unroll
                for (int i = 0; i < RM; i += 4)
                    *(float4*)&af[i] = *(const float4*)&As[kk][ty * RM + i];
#pragma unroll
                for (int j = 0; j < RN; j += 4)
                    *(float4*)&bf[j] = *(const float4*)&Ws[kk][tx * RN + j];
#pragma unroll
                for (int i = 0; i < RM; ++i)
#pragma unroll
                    for (int j = 0; j < RN; ++j)
                        acc[i][j] = fmaf(af[i], bf[j], acc[i][j]);
            }
            __syncthreads();
        }
    }
    float* Cb = C + (size_t)b * LSEQ * ldc;
#pragma unroll
    for (int i = 0; i < RM; ++i) {
        int t = t0 + ty * RM + i;
        if (t >= LSEQ) continue;
#pragma unroll
        for (int j = 0; j < RN; ++j) {
            int n = n0 + tx * RN + j;
            if (n >= Ntot) continue;
            float v = acc[i][j];
            if (epi == 1) {            // bias + batchnorm + relu
                v += bias[n];
                float gg = bn[n], bb = bn[bnN + n], mm = bn[2 * bnN + n], vv = bn[3 * bnN + n];
                v = (v - mm) * (gg / sqrtf(vv + 1e-5f)) + bb;
                v = v > 0.f ? v : 0.f;
            } else if (epi == 2) {     // bias + relu
                v += bias[n];
                v = v > 0.f ? v : 0.f;
            }
            Cb[(size_t)t * ldc + n] = v;
        }
    }
}

// ---------------- layernorm (one wave per 128-dim row) ----------------
__global__ __launch_bounds__(256) void ln_kernel(
    const float* __restrict__ in, const float* __restrict__ g,
    const float* __restrict__ b2, float* __restrict__ out)
{
    int lane = threadIdx.x & 63;
    int wid  = threadIdx.x >> 6;
    int row = blockIdx.x * 4 + wid;
    if (row >= BLROWS) return;
    const float* rp = in + (size_t)row * 128;
    float v0 = rp[lane], v1 = rp[lane + 64];
    float s = v0 + v1;
#pragma unroll
    for (int o2 = 32; o2 > 0; o2 >>= 1) s += __shfl_xor(s, o2, 64);
    float mu = s * (1.f / 128.f);
    float d0 = v0 - mu, d1 = v1 - mu;
    float q = d0 * d0 + d1 * d1;
#pragma unroll
    for (int o2 = 32; o2 > 0; o2 >>= 1) q += __shfl_xor(q, o2, 64);
    float rs = 1.f / sqrtf(q * (1.f / 128.f) + 1e-5f);
    float* op = out + (size_t)row * 128;
    op[lane]      = d0 * rs * g[lane]      + b2[lane];
    op[lane + 64] = d1 * rs * g[lane + 64] + b2[lane + 64];
}

// ---------------- depthwise causal conv (K=4) + silu ----------------
__global__ __launch_bounds__(256) void mconv_kernel(
    const float* __restrict__ xz, const float* __restrict__ Wc,
    const float* __restrict__ bc, float* __restrict__ u)
{
    int idx = blockIdx.x * 256 + threadIdx.x;
    int c = idx & 255;
    int r = idx >> 8;
    if (r >= BLROWS) return;
    int t = r % LSEQ;
    const float* xs = xz + (size_t)r * 512 + c;
    float acc = bc[c];
    if (t >= 3) acc = fmaf(xs[-3 * 512], Wc[c * 4 + 0], acc);
    if (t >= 2) acc = fmaf(xs[-2 * 512], Wc[c * 4 + 1], acc);
    if (t >= 1) acc = fmaf(xs[-1 * 512], Wc[c * 4 + 2], acc);
    acc = fmaf(xs[0], Wc[c * 4 + 3], acc);
    u[(size_t)r * 256 + c] = silu_f(acc);
}

// ---------------- dt = softplus(dbl[:, :8] @ dt_W.T + dt_b) ----------------
__global__ __launch_bounds__(256) void dtk_kernel(
    const float* __restrict__ dbl, const float* __restrict__ dtW,
    const float* __restrict__ dtb, float* __restrict__ dtout)
{
    int idx = blockIdx.x * 256 + threadIdx.x;
    int c = idx & 255;
    int r = idx >> 8;
    if (r >= BLROWS) return;
    const float* dr = dbl + (size_t)r * 40;
    float a = dtb[c];
#pragma unroll
    for (int j = 0; j < 8; ++j) a = fmaf(dr[j], dtW[c * 8 + j], a);
    float sp = (a > 20.f) ? a : log1pf(__expf(a));
    dtout[(size_t)r * 256 + c] = sp;
}

// ---------------- selective scan: 3-pass chunked linear scan ----------------
__global__ __launch_bounds__(256) void scan1_kernel(
    const float* __restrict__ dt, const float* __restrict__ u,
    const float* __restrict__ dbl, const float* __restrict__ Alog,
    float* __restrict__ P, float* __restrict__ S)
{
    int idx = blockIdx.x * 256 + threadIdx.x;
    int d = idx & 255;
    int rest = idx >> 8;
    int ch = rest % CHN;
    int b  = rest / CHN;
    float A2[16];
#pragma unroll
    for (int n = 0; n < 16; ++n) A2[n] = -__expf(Alog[d * 16 + n]);
    float p[16], s[16];
#pragma unroll
    for (int n = 0; n < 16; ++n) { p[n] = 1.f; s[n] = 0.f; }
    int r0 = b * LSEQ + ch * LCH;
    for (int q = 0; q < LCH; ++q) {
        size_t r = (size_t)(r0 + q);
        float dtv = dt[r * 256 + d];
        float uv  = u [r * 256 + d];
        float dtu = dtv * uv;
        const float* Br = dbl + r * 40 + 8;
#pragma unroll
        for (int n = 0; n < 16; ++n) {
            float a = __expf(dtv * A2[n]);
            p[n] *= a;
            s[n] = fmaf(a, s[n], dtu * Br[n]);
        }
    }
    size_t ob = ((size_t)(b * CHN + ch) * 256 + d) * 16;
#pragma unroll
    for (int n = 0; n < 16; ++n) { P[ob + n] = p[n]; S[ob + n] = s[n]; }
}

__global__ __launch_bounds__(256) void scan2_kernel(
    const float* __restrict__ P, const float* __restrict__ S, float* __restrict__ H0)
{
    int idx = blockIdx.x * 256 + threadIdx.x;   // 65536 = 16*256*16
    int n = idx & 15;
    int d = (idx >> 4) & 255;
    int b = idx >> 12;
    float h = 0.f;
    for (int ch = 0; ch < CHN; ++ch) {
        size_t o = ((size_t)(b * CHN + ch) * 256 + d) * 16 + n;
        H0[o] = h;
        h = fmaf(P[o], h, S[o]);
    }
}

__global__ __launch_bounds__(256) void scan3_kernel(
    const float* __restrict__ dt, const float* __restrict__ u,
    const float* __restrict__ dbl, const float* __restrict__ Alog,
    const float* __restrict__ H0, const float* __restrict__ Dp,
    const float* __restrict__ xz, float* __restrict__ g)
{
    int idx = blockIdx.x * 256 + threadIdx.x;
    int d = idx & 255;
    int rest = idx >> 8;
    int ch = rest % CHN;
    int b  = rest / CHN;
    float A2[16];
#pragma unroll
    for (int n = 0; n < 16; ++n) A2[n] = -__expf(Alog[d * 16 + n]);
    float h[16];
    size_t ob = ((size_t)(b * CHN + ch) * 256 + d) * 16;
#pragma unroll
    for (int n = 0; n < 16; ++n) h[n] = H0[ob + n];
    float Dpd = Dp[d];
    int r0 = b * LSEQ + ch * LCH;
    for (int q = 0; q < LCH; ++q) {
        size_t r = (size_t)(r0 + q);
        float dtv = dt[r * 256 + d];
        float uv  = u [r * 256 + d];
        float dtu = dtv * uv;
        const float* Br = dbl + r * 40 + 8;
        const float* Cr = dbl + r * 40 + 24;
        float acc = 0.f;
#pragma unroll
        for (int n = 0; n < 16; ++n) {
            float a = __expf(dtv * A2[n]);
            h[n] = fmaf(a, h[n], dtu * Br[n]);
            acc = fmaf(h[n], Cr[n], acc);
        }
        float yv = fmaf(uv, Dpd, acc);
        float zv = xz[r * 512 + 256 + d];
        g[r * 256 + d] = yv * silu_f(zv);
    }
}

// ---------------- mean pool + final fc ----------------
__global__ __launch_bounds__(128) void pool1_kernel(
    const float* __restrict__ fused, float* __restrict__ part)
{
    int d = threadIdx.x;           // 128
    int blk = blockIdx.x;          // 16*27
    int ch = blk % CHN;
    int b  = blk / CHN;
    int t0 = ch * LCH;
    float s = 0.f;
    for (int q = 0; q < LCH; ++q)
        s += fused[((size_t)(b * LSEQ + t0 + q)) * 128 + d];
    part[(size_t)(b * CHN + ch) * 128 + d] = s;
}

__global__ __launch_bounds__(128) void pool2_kernel(
    const float* __restrict__ part, const float* __restrict__ fcW,
    const float* __restrict__ fcb, float* __restrict__ out)
{
    __shared__ float pl[128];
    int d = threadIdx.x;
    int b = blockIdx.x;
    float s = 0.f;
    for (int ch = 0; ch < CHN; ++ch) s += part[(size_t)(b * CHN + ch) * 128 + d];
    pl[d] = s * (1.f / 1080.f);
    __syncthreads();
    if (d < 3) {
        float a = fcb[d];
        for (int dd = 0; dd < 128; ++dd) a = fmaf(pl[dd], fcW[d * 128 + dd], a);
        out[b * 3 + d] = a;
    }
}

// ---------------- host orchestration ----------------
extern "C" void kernel_launch(void* const* d_in, const int* in_sizes, int n_in,
                              void* d_out, int out_size, void* d_ws, size_t ws_size,
                              hipStream_t stream)
{
    const float* x    = (const float*)d_in[0];
    const float* embW = (const float*)d_in[1];
    const float* embb = (const float*)d_in[2];
    const float* c3W  = (const float*)d_in[3];
    const float* c3b  = (const float*)d_in[4];
    const float* bn3  = (const float*)d_in[5];
    const float* c5W  = (const float*)d_in[6];
    const float* c5b  = (const float*)d_in[7];
    const float* bn5  = (const float*)d_in[8];
    const float* c7W  = (const float*)d_in[9];
    const float* c7b  = (const float*)d_in[10];
    const float* bn7  = (const float*)d_in[11];
    const float* cfW  = (const float*)d_in[12];
    const float* cfb  = (const float*)d_in[13];
    const float* bnf  = (const float*)d_in[14];
    const float* lng  = (const float*)d_in[15];
    const float* lnb  = (const float*)d_in[16];
    const float* inW  = (const float*)d_in[17];
    const float* mcW  = (const float*)d_in[18];
    const float* mcb  = (const float*)d_in[19];
    const float* xpW  = (const float*)d_in[20];
    const float* dtW  = (const float*)d_in[21];
    const float* dtbp = (const float*)d_in[22];
    const float* Alog = (const float*)d_in[23];
    const float* Dp   = (const float*)d_in[24];
    const float* outW = (const float*)d_in[25];
    const float* flW  = (const float*)d_in[26];
    const float* flb  = (const float*)d_in[27];
    const float* fcW  = (const float*)d_in[28];
    const float* fcb  = (const float*)d_in[29];

    float* ws = (float*)d_ws;
    size_t off = 0;
    auto alloc = [&](size_t n) { float* p = ws + off; off += n; return p; };
    float* xe   = alloc((size_t)BLROWS * 128);
    float* lnx  = alloc((size_t)BLROWS * 128);   // reused later as 'fused'
    float* xz   = alloc((size_t)BLROWS * 512);
    float* ub   = alloc((size_t)BLROWS * 256);
    float* dtt  = alloc((size_t)BLROWS * 256);
    float* dbl  = alloc((size_t)BLROWS * 40);
    float* gb   = alloc((size_t)BLROWS * 256);   // first 192 cols double as 'cc'
    float* mbuf = alloc((size_t)BLROWS * 128);
    float* fin  = alloc((size_t)BLROWS * 256);
    float* Pb   = alloc((size_t)NBATCH * CHN * 256 * 16);  // reused as pool partials
    float* Sb   = alloc((size_t)NBATCH * CHN * 256 * 16);
    float* h0b  = alloc((size_t)NBATCH * CHN * 256 * 16);
    float* cc    = gb;
    float* fused = lnx;
    (void)ws_size; (void)in_sizes; (void)n_in; (void)out_size;

    // 1. embedding + positional encoding
    embed_kernel<<<(BLROWS * 128) / 256, 256, 0, stream>>>(x, embW, embb, xe);

    // 2. CNN branch: three tap-convs -> cc, then 1x1 fuse -> fin[:, 0:128]
    dim3 gconv(1, (LSEQ + 63) / 64, NBATCH);
    gemm_kernel<4, 4><<<gconv, 256, 0, stream>>>(xe, 128, c3W, 128 * 3, 64, 128, 3, 1,
                                                 c3b, bn3, 64, 1, cc, 192);
    gemm_kernel<4, 4><<<gconv, 256, 0, stream>>>(xe, 128, c5W, 128 * 5, 64, 128, 5, 2,
                                                 c5b, bn5, 64, 1, cc + 64, 192);
    gemm_kernel<4, 4><<<gconv, 256, 0, stream>>>(xe, 128, c7W, 128 * 7, 64, 128, 7, 3,
                                                 c7b, bn7, 64, 1, cc + 128, 192);
    dim3 gcf(1, (LSEQ + 127) / 128, NBATCH);
    gemm_kernel<8, 8><<<gcf, 256, 0, stream>>>(cc, 192, cfW, 192, 128, 192, 1, 0,
                                               cfb, bnf, 128, 1, fin, 256);

    // 3. three mamba blocks
    for (int i = 0; i < 3; ++i) {
        const float* min_ = (i == 0) ? xe : ((i == 1) ? mbuf : xe);
        float* mout = (i == 0) ? mbuf : ((i == 1) ? xe : (fin + 128));
        int ldout = (i < 2) ? 128 : 256;

        ln_kernel<<<BLROWS / 4, 256, 0, stream>>>(min_, lng + i * 128, lnb + i * 128, lnx);

        dim3 gin(4, (LSEQ + 127) / 128, NBATCH);
        gemm_kernel<8, 8><<<gin, 256, 0, stream>>>(lnx, 128, inW + (size_t)i * 512 * 128, 128,
                                                   512, 128, 1, 0, nullptr, nullptr, 0, 0,
                                                   xz, 512);

        mconv_kernel<<<BLROWS, 256, 0, stream>>>(xz, mcW + i * 256 * 4, mcb + i * 256, ub);

        dim3 gxp(1, (LSEQ + 63) / 64, NBATCH);
        gemm_kernel<4, 4><<<gxp, 256, 0, stream>>>(ub, 256, xpW + (size_t)i * 40 * 256, 256,
                                                   40, 256, 1, 0, nullptr, nullptr, 0, 0,
                                                   dbl, 40);

        dtk_kernel<<<BLROWS, 256, 0, stream>>>(dbl, dtW + i * 256 * 8, dtbp + i * 256, dtt);

        scan1_kernel<<<(NBATCH * 256 * CHN) / 256, 256, 0, stream>>>(
            dtt, ub, dbl, Alog + i * 256 * 16, Pb, Sb);
        scan2_kernel<<<(NBATCH * 256 * 16) / 256, 256, 0, stream>>>(Pb, Sb, h0b);
        scan3_kernel<<<(NBATCH * 256 * CHN) / 256, 256, 0, stream>>>(
            dtt, ub, dbl, Alog + i * 256 * 16, h0b, Dp + i * 256, xz, gb);

        dim3 gop(1, (LSEQ + 127) / 128, NBATCH);
        gemm_kernel<8, 8><<<gop, 256, 0, stream>>>(gb, 256, outW + (size_t)i * 128 * 256, 256,
                                                   128, 256, 1, 0, nullptr, nullptr, 0, 0,
                                                   mout, ldout);
    }

    // 4. fusion linear + relu -> fused (reuses lnx)
    dim3 gfl(1, (LSEQ + 127) / 128, NBATCH);
    gemm_kernel<8, 8><<<gfl, 256, 0, stream>>>(fin, 256, flW, 256, 128, 256, 1, 0,
                                               flb, nullptr, 0, 2, fused, 128);

    // 5. mean pool over t + final fc
    pool1_kernel<<<NBATCH * CHN, 128, 0, stream>>>(fused, Pb);
    pool2_kernel<<<NBATCH, 128, 0, stream>>>(Pb, fcW, fcb, (float*)d_out);
}

// Round 2
// 795.839 us; speedup vs baseline: 1.5677x; 1.5677x over previous
//
#include <hip/hip_runtime.h>
#include <math.h>

#define LSEQ   1080
#define NBATCH 16
#define BLROWS (LSEQ*NBATCH)   // 17280
#define CHN    27
#define LCH    40              // 27*40 = 1080

typedef __bf16  bf16x8 __attribute__((ext_vector_type(8)));
typedef float   f32x4  __attribute__((ext_vector_type(4)));
typedef short   short8 __attribute__((ext_vector_type(8)));
typedef short   short4v __attribute__((ext_vector_type(4)));

__device__ __forceinline__ float silu_f(float x) { return x / (1.f + __expf(-x)); }

__device__ __forceinline__ unsigned short f2bf(float f) {
    unsigned int u = __float_as_uint(f);
    u += 0x7fffu + ((u >> 16) & 1u);
    return (unsigned short)(u >> 16);
}
__device__ __forceinline__ float bf2f(unsigned short h) {
    return __uint_as_float(((unsigned int)h) << 16);
}

// ---------------- embed + positional encoding ----------------
__global__ __launch_bounds__(256) void embed_kernel(
    const float* __restrict__ x, const float* __restrict__ embW,
    const float* __restrict__ embb, float* __restrict__ xe)
{
    int idx = blockIdx.x * 256 + threadIdx.x;
    if (idx >= BLROWS * 128) return;
    int d = idx & 127;
    int r = idx >> 7;
    int t = r % LSEQ;
    float x0 = x[(size_t)r * 2], x1 = x[(size_t)r * 2 + 1];
    int i2 = d & 126;
    float div = expf((float)i2 * (-9.210340371976184f / 128.f));
    float arg = (float)t * div;
    float pe = (d & 1) ? cosf(arg) : sinf(arg);
    xe[idx] = fmaf(x0, embW[d], fmaf(x1, embW[128 + d], embb[d] + pe));
}

// ---------------- weight fp32 -> (hi,lo) bf16 conversion ----------------
// plain row-major [NBk][N][K] -> [NBk][Npad][K], rows >= N zero-filled
__global__ __launch_bounds__(256) void convw_kernel(
    const float* __restrict__ src, unsigned short* __restrict__ dh,
    unsigned short* __restrict__ dl, int NBk, int N, int Npad, int K)
{
    int idx = blockIdx.x * 256 + threadIdx.x;
    int total = NBk * Npad * K;
    if (idx >= total) return;
    int k = idx % K;
    int n = (idx / K) % Npad;
    int blk = idx / (K * Npad);
    float v = (n < N) ? src[((size_t)blk * N + n) * K + k] : 0.f;
    unsigned short h = f2bf(v);
    dh[idx] = h;
    dl[idx] = f2bf(v - bf2f(h));
}

// conv taps: src [64][128][T] -> dst [64][T*128] (kk = tap*128 + d)
__global__ __launch_bounds__(256) void convw_conv_kernel(
    const float* __restrict__ src, unsigned short* __restrict__ dh,
    unsigned short* __restrict__ dl, int T)
{
    int idx = blockIdx.x * 256 + threadIdx.x;
    int total = 64 * 128 * T;
    if (idx >= total) return;
    int kk = idx % (128 * T);
    int n = idx / (128 * T);
    int tap = kk / 128, d = kk % 128;
    float v = src[((size_t)n * 128 + d) * T + tap];
    unsigned short h = f2bf(v);
    dh[idx] = h;
    dl[idx] = f2bf(v - bf2f(h));
}

// ---------------- MFMA split-bf16 GEMM with conv taps + epilogues ----------
// C[b,t,n] = epi( sum_{tap,d} A[b,t+tap-pad,d] * Wrow[n][tap*Kd+d] )
// W pre-converted to (hi,lo) bf16, row length Kd*KT, rows padded to grid N.
template<int BM, int BN>
__global__ __launch_bounds__(256) void gemm_mfma(
    const float* __restrict__ A, int lda,
    const unsigned short* __restrict__ Wh, const unsigned short* __restrict__ Wl,
    int Ntot, int Kd, int KT, int pad,
    const float* __restrict__ bias, const float* __restrict__ bn, int bnN, int epi,
    float* __restrict__ C, int ldc)
{
    constexpr int WM = BM / 2, WN = BN / 2;
    constexpr int MR = WM / 16, NR = WN / 16;
    constexpr int LA = (BM * 8) / 256;   // float4 chunks of A per thread
    constexpr int LB = (BN * 4) / 256;   // short8 chunks of W per thread

    __shared__ unsigned short Ah[BM][40], Al[BM][40];
    __shared__ unsigned short Bh[BN][40], Bl[BN][40];

    const int tid = threadIdx.x;
    const int b  = blockIdx.z;
    const int t0 = blockIdx.y * BM;
    const int n0 = blockIdx.x * BN;
    const float* Ab = A + (size_t)b * LSEQ * lda;
    const int wrow = Kd * KT;

    const int lane = tid & 63, wid = tid >> 6;
    const int wr = wid >> 1, wc = wid & 1;
    const int fr = lane & 15, fq = lane >> 4;

    f32x4 acc[MR][NR];
#pragma unroll
    for (int m = 0; m < MR; ++m)
#pragma unroll
        for (int n = 0; n < NR; ++n) acc[m][n] = (f32x4){0.f, 0.f, 0.f, 0.f};

    for (int tap = 0; tap < KT; ++tap) {
        const int shift = tap - pad;
        for (int ks = 0; ks < Kd; ks += 32) {
            // ---- stage A: fp32 -> hi/lo bf16 ----
#pragma unroll
            for (int l = 0; l < LA; ++l) {
                int c = tid + l * 256;
                int row = c >> 3, kc = (c & 7) << 2;
                int ts = t0 + row + shift;
                float4 av = make_float4(0.f, 0.f, 0.f, 0.f);
                if (ts >= 0 && ts < LSEQ)
                    av = *(const float4*)(Ab + (size_t)ts * lda + ks + kc);
                alignas(8) unsigned short hs[4], ls[4];
                float fv[4] = {av.x, av.y, av.z, av.w};
#pragma unroll
                for (int j = 0; j < 4; ++j) {
                    unsigned short h = f2bf(fv[j]);
                    hs[j] = h;
                    ls[j] = f2bf(fv[j] - bf2f(h));
                }
                *(short4v*)&Ah[row][kc] = *(short4v*)hs;
                *(short4v*)&Al[row][kc] = *(short4v*)ls;
            }
            // ---- stage B: copy pre-converted bf16 ----
            const int kglob = tap * Kd + ks;
#pragma unroll
            for (int l = 0; l < LB; ++l) {
                int c = tid + l * 256;
                int col = c >> 2, kc = (c & 3) << 3;
                size_t src = (size_t)(n0 + col) * wrow + kglob + kc;
                *(short8*)&Bh[col][kc] = *(const short8*)&Wh[src];
                *(short8*)&Bl[col][kc] = *(const short8*)&Wl[src];
            }
            __syncthreads();
            // ---- fragments + MFMA ----
            bf16x8 bhf[NR], blf[NR];
#pragma unroll
            for (int n = 0; n < NR; ++n) {
                int colr = wc * WN + n * 16 + fr;
                bhf[n] = __builtin_bit_cast(bf16x8, *(const short8*)&Bh[colr][fq * 8]);
                blf[n] = __builtin_bit_cast(bf16x8, *(const short8*)&Bl[colr][fq * 8]);
            }
#pragma unroll
            for (int m = 0; m < MR; ++m) {
                int rowr = wr * WM + m * 16 + fr;
                bf16x8 ahf = __builtin_bit_cast(bf16x8, *(const short8*)&Ah[rowr][fq * 8]);
                bf16x8 alf = __builtin_bit_cast(bf16x8, *(const short8*)&Al[rowr][fq * 8]);
#pragma unroll
                for (int n = 0; n < NR; ++n) {
                    acc[m][n] = __builtin_amdgcn_mfma_f32_16x16x32_bf16(ahf, bhf[n], acc[m][n], 0, 0, 0);
                    acc[m][n] = __builtin_amdgcn_mfma_f32_16x16x32_bf16(ahf, blf[n], acc[m][n], 0, 0, 0);
                    acc[m][n] = __builtin_amdgcn_mfma_f32_16x16x32_bf16(alf, bhf[n], acc[m][n], 0, 0, 0);
                }
            }
            __syncthreads();
        }
    }

    // ---- epilogue ----
    float* Cb = C + (size_t)b * LSEQ * ldc;
#pragma unroll
    for (int m = 0; m < MR; ++m) {
#pragma unroll
        for (int n = 0; n < NR; ++n) {
            int colg = n0 + wc * WN + n * 16 + fr;
            if (colg >= Ntot) continue;
#pragma unroll
            for (int r = 0; r < 4; ++r) {
                int t = t0 + wr * WM + m * 16 + fq * 4 + r;
                if (t >= LSEQ) continue;
                float v = acc[m][n][r];
                if (epi == 1) {
                    v += bias[colg];
                    float gg = bn[colg], bb = bn[bnN + colg];
                    float mm = bn[2 * bnN + colg], vv = bn[3 * bnN + colg];
                    v = (v - mm) * (gg / sqrtf(vv + 1e-5f)) + bb;
                    v = v > 0.f ? v : 0.f;
                } else if (epi == 2) {
                    v += bias[colg];
                    v = v > 0.f ? v : 0.f;
                }
                Cb[(size_t)t * ldc + colg] = v;
            }
        }
    }
}

// ---------------- layernorm (one wave per 128-dim row) ----------------
__global__ __launch_bounds__(256) void ln_kernel(
    const float* __restrict__ in, const float* __restrict__ g,
    const float* __restrict__ b2, float* __restrict__ out)
{
    int lane = threadIdx.x & 63;
    int wid  = threadIdx.x >> 6;
    int row = blockIdx.x * 4 + wid;
    if (row >= BLROWS) return;
    const float* rp = in + (size_t)row * 128;
    float v0 = rp[lane], v1 = rp[lane + 64];
    float s = v0 + v1;
#pragma unroll
    for (int o2 = 32; o2 > 0; o2 >>= 1) s += __shfl_xor(s, o2, 64);
    float mu = s * (1.f / 128.f);
    float d0 = v0 - mu, d1 = v1 - mu;
    float q = d0 * d0 + d1 * d1;
#pragma unroll
    for (int o2 = 32; o2 > 0; o2 >>= 1) q += __shfl_xor(q, o2, 64);
    float rs = 1.f / sqrtf(q * (1.f / 128.f) + 1e-5f);
    float* op = out + (size_t)row * 128;
    op[lane]      = d0 * rs * g[lane]      + b2[lane];
    op[lane + 64] = d1 * rs * g[lane + 64] + b2[lane + 64];
}

// ---------------- depthwise causal conv (K=4) + silu ----------------
__global__ __launch_bounds__(256) void mconv_kernel(
    const float* __restrict__ xz, const float* __restrict__ Wc,
    const float* __restrict__ bc, float* __restrict__ u)
{
    int idx = blockIdx.x * 256 + threadIdx.x;
    int c = idx & 255;
    int r = idx >> 8;
    if (r >= BLROWS) return;
    int t = r % LSEQ;
    const float* xs = xz + (size_t)r * 512 + c;
    float acc = bc[c];
    if (t >= 3) acc = fmaf(xs[-3 * 512], Wc[c * 4 + 0], acc);
    if (t >= 2) acc = fmaf(xs[-2 * 512], Wc[c * 4 + 1], acc);
    if (t >= 1) acc = fmaf(xs[-1 * 512], Wc[c * 4 + 2], acc);
    acc = fmaf(xs[0], Wc[c * 4 + 3], acc);
    u[(size_t)r * 256 + c] = silu_f(acc);
}

// ---------------- dt = softplus(dbl[:, :8] @ dt_W.T + dt_b) ----------------
__global__ __launch_bounds__(256) void dtk_kernel(
    const float* __restrict__ dbl, const float* __restrict__ dtW,
    const float* __restrict__ dtb, float* __restrict__ dtout)
{
    int idx = blockIdx.x * 256 + threadIdx.x;
    int c = idx & 255;
    int r = idx >> 8;
    if (r >= BLROWS) return;
    const float* dr = dbl + (size_t)r * 40;
    float a = dtb[c];
#pragma unroll
    for (int j = 0; j < 8; ++j) a = fmaf(dr[j], dtW[c * 8 + j], a);
    float sp = (a > 20.f) ? a : log1pf(__expf(a));
    dtout[(size_t)r * 256 + c] = sp;
}

// ---------------- selective scan: 3-pass chunked linear scan ----------------
__global__ __launch_bounds__(256) void scan1_kernel(
    const float* __restrict__ dt, const float* __restrict__ u,
    const float* __restrict__ dbl, const float* __restrict__ Alog,
    float* __restrict__ P, float* __restrict__ S)
{
    int idx = blockIdx.x * 256 + threadIdx.x;
    int d = idx & 255;
    int rest = idx >> 8;
    int ch = rest % CHN;
    int b  = rest / CHN;
    float A2[16];
#pragma unroll
    for (int n = 0; n < 16; ++n) A2[n] = -__expf(Alog[d * 16 + n]);
    float p[16], s[16];
#pragma unroll
    for (int n = 0; n < 16; ++n) { p[n] = 1.f; s[n] = 0.f; }
    int r0 = b * LSEQ + ch * LCH;
    for (int q = 0; q < LCH; ++q) {
        size_t r = (size_t)(r0 + q);
        float dtv = dt[r * 256 + d];
        float uv  = u [r * 256 + d];
        float dtu = dtv * uv;
        const float* Br = dbl + r * 40 + 8;
#pragma unroll
        for (int n = 0; n < 16; ++n) {
            float a = __expf(dtv * A2[n]);
            p[n] *= a;
            s[n] = fmaf(a, s[n], dtu * Br[n]);
        }
    }
    size_t ob = ((size_t)(b * CHN + ch) * 256 + d) * 16;
#pragma unroll
    for (int n = 0; n < 16; ++n) { P[ob + n] = p[n]; S[ob + n] = s[n]; }
}

__global__ __launch_bounds__(256) void scan2_kernel(
    const float* __restrict__ P, const float* __restrict__ S, float* __restrict__ H0)
{
    int idx = blockIdx.x * 256 + threadIdx.x;   // 65536 = 16*256*16
    int n = idx & 15;
    int d = (idx >> 4) & 255;
    int b = idx >> 12;
    float h = 0.f;
    for (int ch = 0; ch < CHN; ++ch) {
        size_t o = ((size_t)(b * CHN + ch) * 256 + d) * 16 + n;
        H0[o] = h;
        h = fmaf(P[o], h, S[o]);
    }
}

__global__ __launch_bounds__(256) void scan3_kernel(
    const float* __restrict__ dt, const float* __restrict__ u,
    const float* __restrict__ dbl, const float* __restrict__ Alog,
    const float* __restrict__ H0, const float* __restrict__ Dp,
    const float* __restrict__ xz, float* __restrict__ g)
{
    int idx = blockIdx.x * 256 + threadIdx.x;
    int d = idx & 255;
    int rest = idx >> 8;
    int ch = rest % CHN;
    int b  = rest / CHN;
    float A2[16];
#pragma unroll
    for (int n = 0; n < 16; ++n) A2[n] = -__expf(Alog[d * 16 + n]);
    float h[16];
    size_t ob = ((size_t)(b * CHN + ch) * 256 + d) * 16;
#pragma unroll
    for (int n = 0; n < 16; ++n) h[n] = H0[ob + n];
    float Dpd = Dp[d];
    int r0 = b * LSEQ + ch * LCH;
    for (int q = 0; q < LCH; ++q) {
        size_t r = (size_t)(r0 + q);
        float dtv = dt[r * 256 + d];
        float uv  = u [r * 256 + d];
        float dtu = dtv * uv;
        const float* Br = dbl + r * 40 + 8;
        const float* Cr = dbl + r * 40 + 24;
        float acc = 0.f;
#pragma unroll
        for (int n = 0; n < 16; ++n) {
            float a = __expf(dtv * A2[n]);
            h[n] = fmaf(a, h[n], dtu * Br[n]);
            acc = fmaf(h[n], Cr[n], acc);
        }
        float yv = fmaf(uv, Dpd, acc);
        float zv = xz[r * 512 + 256 + d];
        g[r * 256 + d] = yv * silu_f(zv);
    }
}

// ---------------- mean pool + final fc ----------------
__global__ __launch_bounds__(128) void pool1_kernel(
    const float* __restrict__ fused, float* __restrict__ part)
{
    int d = threadIdx.x;
    int blk = blockIdx.x;
    int ch = blk % CHN;
    int b  = blk / CHN;
    int t0 = ch * LCH;
    float s = 0.f;
    for (int q = 0; q < LCH; ++q)
        s += fused[((size_t)(b * LSEQ + t0 + q)) * 128 + d];
    part[(size_t)(b * CHN + ch) * 128 + d] = s;
}

__global__ __launch_bounds__(128) void pool2_kernel(
    const float* __restrict__ part, const float* __restrict__ fcW,
    const float* __restrict__ fcb, float* __restrict__ out)
{
    __shared__ float pl[128];
    int d = threadIdx.x;
    int b = blockIdx.x;
    float s = 0.f;
    for (int ch = 0; ch < CHN; ++ch) s += part[(size_t)(b * CHN + ch) * 128 + d];
    pl[d] = s * (1.f / 1080.f);
    __syncthreads();
    if (d < 3) {
        float a = fcb[d];
        for (int dd = 0; dd < 128; ++dd) a = fmaf(pl[dd], fcW[d * 128 + dd], a);
        out[b * 3 + d] = a;
    }
}

// ---------------- host orchestration ----------------
extern "C" void kernel_launch(void* const* d_in, const int* in_sizes, int n_in,
                              void* d_out, int out_size, void* d_ws, size_t ws_size,
                              hipStream_t stream)
{
    const float* x    = (const float*)d_in[0];
    const float* embW = (const float*)d_in[1];
    const float* embb = (const float*)d_in[2];
    const float* c3W  = (const float*)d_in[3];
    const float* c3b  = (const float*)d_in[4];
    const float* bn3  = (const float*)d_in[5];
    const float* c5W  = (const float*)d_in[6];
    const float* c5b  = (const float*)d_in[7];
    const float* bn5  = (const float*)d_in[8];
    const float* c7W  = (const float*)d_in[9];
    const float* c7b  = (const float*)d_in[10];
    const float* bn7  = (const float*)d_in[11];
    const float* cfW  = (const float*)d_in[12];
    const float* cfb  = (const float*)d_in[13];
    const float* bnf  = (const float*)d_in[14];
    const float* lng  = (const float*)d_in[15];
    const float* lnb  = (const float*)d_in[16];
    const float* inW  = (const float*)d_in[17];
    const float* mcW  = (const float*)d_in[18];
    const float* mcb  = (const float*)d_in[19];
    const float* xpW  = (const float*)d_in[20];
    const float* dtW  = (const float*)d_in[21];
    const float* dtbp = (const float*)d_in[22];
    const float* Alog = (const float*)d_in[23];
    const float* Dp   = (const float*)d_in[24];
    const float* outW = (const float*)d_in[25];
    const float* flW  = (const float*)d_in[26];
    const float* flb  = (const float*)d_in[27];
    const float* fcW  = (const float*)d_in[28];
    const float* fcb  = (const float*)d_in[29];

    float* ws = (float*)d_ws;
    size_t off = 0;
    auto alloc = [&](size_t n) { float* p = ws + off; off += n; return p; };
    float* xe   = alloc((size_t)BLROWS * 128);
    float* lnx  = alloc((size_t)BLROWS * 128);   // reused later as 'fused'
    float* xz   = alloc((size_t)BLROWS * 512);
    float* ub   = alloc((size_t)BLROWS * 256);
    float* dtt  = alloc((size_t)BLROWS * 256);
    float* dbl  = alloc((size_t)BLROWS * 40);
    float* gb   = alloc((size_t)BLROWS * 256);   // first 192 cols double as 'cc'
    float* mbuf = alloc((size_t)BLROWS * 128);
    float* fin  = alloc((size_t)BLROWS * 256);
    float* Pb   = alloc((size_t)NBATCH * CHN * 256 * 16);  // reused as pool partials
    float* Sb   = alloc((size_t)NBATCH * CHN * 256 * 16);
    float* h0b  = alloc((size_t)NBATCH * CHN * 256 * 16);
    float* cc    = gb;
    float* fused = lnx;

    // bf16 hi/lo weight buffers (ushort), 16B-aligned
    off = (off + 3) & ~(size_t)3;
    unsigned short* us = (unsigned short*)(ws + off);
    size_t uo = 0;
    auto ualloc = [&](size_t n) { unsigned short* p = us + uo; uo += n; return p; };
    unsigned short* c3h = ualloc(64 * 384);  unsigned short* c3l = ualloc(64 * 384);
    unsigned short* c5h = ualloc(64 * 640);  unsigned short* c5l = ualloc(64 * 640);
    unsigned short* c7h = ualloc(64 * 896);  unsigned short* c7l = ualloc(64 * 896);
    unsigned short* cfh = ualloc(128 * 192); unsigned short* cfl = ualloc(128 * 192);
    unsigned short* inh = ualloc((size_t)1536 * 128); unsigned short* inl = ualloc((size_t)1536 * 128);
    unsigned short* xph = ualloc((size_t)3 * 64 * 256); unsigned short* xpl = ualloc((size_t)3 * 64 * 256);
    unsigned short* oth = ualloc((size_t)384 * 256); unsigned short* otl = ualloc((size_t)384 * 256);
    unsigned short* flh = ualloc((size_t)128 * 256); unsigned short* fll = ualloc((size_t)128 * 256);
    (void)ws_size; (void)in_sizes; (void)n_in; (void)out_size;

    // 0. weight conversions
    convw_conv_kernel<<<(64 * 384 + 255) / 256, 256, 0, stream>>>(c3W, c3h, c3l, 3);
    convw_conv_kernel<<<(64 * 640 + 255) / 256, 256, 0, stream>>>(c5W, c5h, c5l, 5);
    convw_conv_kernel<<<(64 * 896 + 255) / 256, 256, 0, stream>>>(c7W, c7h, c7l, 7);
    convw_kernel<<<(128 * 192 + 255) / 256, 256, 0, stream>>>(cfW, cfh, cfl, 1, 128, 128, 192);
    convw_kernel<<<(1536 * 128 + 255) / 256, 256, 0, stream>>>(inW, inh, inl, 1, 1536, 1536, 128);
    convw_kernel<<<(3 * 64 * 256 + 255) / 256, 256, 0, stream>>>(xpW, xph, xpl, 3, 40, 64, 256);
    convw_kernel<<<(384 * 256 + 255) / 256, 256, 0, stream>>>(outW, oth, otl, 1, 384, 384, 256);
    convw_kernel<<<(128 * 256 + 255) / 256, 256, 0, stream>>>(flW, flh, fll, 1, 128, 128, 256);

    // 1. embedding + positional encoding
    embed_kernel<<<(BLROWS * 128) / 256, 256, 0, stream>>>(x, embW, embb, xe);

    // 2. CNN branch
    dim3 g64(1, 17, NBATCH);
    gemm_mfma<64, 64><<<g64, 256, 0, stream>>>(xe, 128, c3h, c3l, 64, 128, 3, 1,
                                               c3b, bn3, 64, 1, cc, 192);
    gemm_mfma<64, 64><<<g64, 256, 0, stream>>>(xe, 128, c5h, c5l, 64, 128, 5, 2,
                                               c5b, bn5, 64, 1, cc + 64, 192);
    gemm_mfma<64, 64><<<g64, 256, 0, stream>>>(xe, 128, c7h, c7l, 64, 128, 7, 3,
                                               c7b, bn7, 64, 1, cc + 128, 192);
    dim3 g128(1, 17, NBATCH);
    gemm_mfma<64, 128><<<g128, 256, 0, stream>>>(cc, 192, cfh, cfl, 128, 192, 1, 0,
                                                 cfb, bnf, 128, 1, fin, 256);

    // 3. three mamba blocks
    for (int i = 0; i < 3; ++i) {
        const float* min_ = (i == 0) ? xe : ((i == 1) ? mbuf : xe);
        float* mout = (i == 0) ? mbuf : ((i == 1) ? xe : (fin + 128));
        int ldout = (i < 2) ? 128 : 256;

        ln_kernel<<<BLROWS / 4, 256, 0, stream>>>(min_, lng + i * 128, lnb + i * 128, lnx);

        dim3 gin(4, 17, NBATCH);
        gemm_mfma<64, 128><<<gin, 256, 0, stream>>>(lnx, 128, inh + (size_t)i * 512 * 128,
                                                    inl + (size_t)i * 512 * 128,
                                                    512, 128, 1, 0, nullptr, nullptr, 0, 0,
                                                    xz, 512);

        mconv_kernel<<<BLROWS, 256, 0, stream>>>(xz, mcW + i * 256 * 4, mcb + i * 256, ub);

        gemm_mfma<64, 64><<<g64, 256, 0, stream>>>(ub, 256, xph + (size_t)i * 64 * 256,
                                                   xpl + (size_t)i * 64 * 256,
                                                   40, 256, 1, 0, nullptr, nullptr, 0, 0,
                                                   dbl, 40);

        dtk_kernel<<<BLROWS, 256, 0, stream>>>(dbl, dtW + i * 256 * 8, dtbp + i * 256, dtt);

        scan1_kernel<<<(NBATCH * 256 * CHN) / 256, 256, 0, stream>>>(
            dtt, ub, dbl, Alog + i * 256 * 16, Pb, Sb);
        scan2_kernel<<<(NBATCH * 256 * 16) / 256, 256, 0, stream>>>(Pb, Sb, h0b);
        scan3_kernel<<<(NBATCH * 256 * CHN) / 256, 256, 0, stream>>>(
            dtt, ub, dbl, Alog + i * 256 * 16, h0b, Dp + i * 256, xz, gb);

        gemm_mfma<64, 128><<<g128, 256, 0, stream>>>(gb, 256, oth + (size_t)i * 128 * 256,
                                                     otl + (size_t)i * 128 * 256,
                                                     128, 256, 1, 0, nullptr, nullptr, 0, 0,
                                                     mout, ldout);
    }

    // 4. fusion linear + relu
    gemm_mfma<64, 128><<<g128, 256, 0, stream>>>(fin, 256, flh, fll, 128, 256, 1, 0,
                                                 flb, nullptr, 0, 2, fused, 128);

    // 5. mean pool + final fc
    pool1_kernel<<<NBATCH * CHN, 128, 0, stream>>>(fused, Pb);
    pool2_kernel<<<NBATCH, 128, 0, stream>>>(Pb, fcW, fcb, (float*)d_out);
}

// Round 3
// 681.997 us; speedup vs baseline: 1.8294x; 1.1669x over previous
//
#include <hip/hip_runtime.h>
#include <math.h>

#define LSEQ   1080
#define NBATCH 16
#define BLROWS (LSEQ*NBATCH)   // 17280
#define CHN    27
#define LCH    40              // 27*40 = 1080

typedef __bf16  bf16x8 __attribute__((ext_vector_type(8)));
typedef float   f32x4  __attribute__((ext_vector_type(4)));
typedef short   short8 __attribute__((ext_vector_type(8)));
typedef short   short4v __attribute__((ext_vector_type(4)));

__device__ __forceinline__ float silu_f(float x) { return x / (1.f + __expf(-x)); }

__device__ __forceinline__ unsigned short f2bf(float f) {
    unsigned int u = __float_as_uint(f);
    u += 0x7fffu + ((u >> 16) & 1u);
    return (unsigned short)(u >> 16);
}
__device__ __forceinline__ float bf2f(unsigned short h) {
    return __uint_as_float(((unsigned int)h) << 16);
}

// ---------------- embed + positional encoding ----------------
__global__ __launch_bounds__(256) void embed_kernel(
    const float* __restrict__ x, const float* __restrict__ embW,
    const float* __restrict__ embb, float* __restrict__ xe)
{
    int idx = blockIdx.x * 256 + threadIdx.x;
    if (idx >= BLROWS * 128) return;
    int d = idx & 127;
    int r = idx >> 7;
    int t = r % LSEQ;
    float x0 = x[(size_t)r * 2], x1 = x[(size_t)r * 2 + 1];
    int i2 = d & 126;
    float div = expf((float)i2 * (-9.210340371976184f / 128.f));
    float arg = (float)t * div;
    float pe = (d & 1) ? cosf(arg) : sinf(arg);
    xe[idx] = fmaf(x0, embW[d], fmaf(x1, embW[128 + d], embb[d] + pe));
}

// ---------------- ALL weight fp32 -> (hi,lo) bf16 conversions, one launch ----
// job offsets (element index space), total = 524288 = 2048 blocks * 256
__global__ __launch_bounds__(256) void convw_all(
    const float* __restrict__ c3W, const float* __restrict__ c5W,
    const float* __restrict__ c7W, const float* __restrict__ cfW,
    const float* __restrict__ inW, const float* __restrict__ xpW,
    const float* __restrict__ otW, const float* __restrict__ flW,
    unsigned short* __restrict__ c3h, unsigned short* __restrict__ c3l,
    unsigned short* __restrict__ c5h, unsigned short* __restrict__ c5l,
    unsigned short* __restrict__ c7h, unsigned short* __restrict__ c7l,
    unsigned short* __restrict__ cfh, unsigned short* __restrict__ cfl,
    unsigned short* __restrict__ inh, unsigned short* __restrict__ inl,
    unsigned short* __restrict__ xph, unsigned short* __restrict__ xpl,
    unsigned short* __restrict__ oth, unsigned short* __restrict__ otl,
    unsigned short* __restrict__ flh, unsigned short* __restrict__ fll)
{
    int idx = blockIdx.x * 256 + threadIdx.x;
    float v;
    unsigned short *dh, *dl;
    int off;
    if (idx < 122880) {            // tap-reorder convs: [64][128][T] -> [64][T*128]
        const float* src; int T;
        if (idx < 24576)      { src = c3W; T = 3; off = idx;          dh = c3h; dl = c3l; }
        else if (idx < 65536) { src = c5W; T = 5; off = idx - 24576;  dh = c5h; dl = c5l; }
        else                  { src = c7W; T = 7; off = idx - 65536;  dh = c7h; dl = c7l; }
        int kk = off % (128 * T);
        int n  = off / (128 * T);
        int tap = kk / 128, d = kk % 128;
        v = src[((size_t)n * 128 + d) * T + tap];
    } else if (idx < 147456) {     // cf: 128x192 plain
        off = idx - 122880; dh = cfh; dl = cfl; v = cfW[off];
    } else if (idx < 344064) {     // in: 1536x128 plain
        off = idx - 147456; dh = inh; dl = inl; v = inW[off];
    } else if (idx < 393216) {     // xp: [3][40->64][256] padded
        off = idx - 344064; dh = xph; dl = xpl;
        int k = off % 256;
        int n = (off / 256) % 64;
        int blk = off / (256 * 64);
        v = (n < 40) ? xpW[((size_t)blk * 40 + n) * 256 + k] : 0.f;
    } else if (idx < 491520) {     // ot: 384x256 plain
        off = idx - 393216; dh = oth; dl = otl; v = otW[off];
    } else {                       // fl: 128x256 plain
        off = idx - 491520; dh = flh; dl = fll; v = flW[off];
    }
    unsigned short h = f2bf(v);
    dh[off] = h;
    dl[off] = f2bf(v - bf2f(h));
}

// ---------------- MFMA split-bf16 GEMM body (shared by wrappers) ------------
// Cb[t,n] += epi( sum_{tap,d} Ab[t+tap-pad, d] * Wrow[n0+n][tap*Kd+d] )
template<int BM, int BN>
__device__ __forceinline__ void gemm_body(
    const float* __restrict__ Ab, int lda,
    const unsigned short* __restrict__ Wh, const unsigned short* __restrict__ Wl,
    int Ntot, int Kd, int KT, int pad,
    const float* __restrict__ bias, const float* __restrict__ bn, int bnN, int epi,
    float* __restrict__ Cb, int ldc, int t0, int n0)
{
    constexpr int WM = BM / 2, WN = BN / 2;
    constexpr int MR = WM / 16, NR = WN / 16;
    constexpr int LA = (BM * 8) / 256;
    constexpr int LB = (BN * 4) / 256;

    __shared__ unsigned short Ah[BM][40], Al[BM][40];
    __shared__ unsigned short Bh[BN][40], Bl[BN][40];

    const int tid = threadIdx.x;
    const int wrow = Kd * KT;
    const int lane = tid & 63, wid = tid >> 6;
    const int wr = wid >> 1, wc = wid & 1;
    const int fr = lane & 15, fq = lane >> 4;

    f32x4 acc[MR][NR];
#pragma unroll
    for (int m = 0; m < MR; ++m)
#pragma unroll
        for (int n = 0; n < NR; ++n) acc[m][n] = (f32x4){0.f, 0.f, 0.f, 0.f};

    for (int tap = 0; tap < KT; ++tap) {
        const int shift = tap - pad;
        for (int ks = 0; ks < Kd; ks += 32) {
#pragma unroll
            for (int l = 0; l < LA; ++l) {
                int c = tid + l * 256;
                int row = c >> 3, kc = (c & 7) << 2;
                int ts = t0 + row + shift;
                float4 av = make_float4(0.f, 0.f, 0.f, 0.f);
                if (ts >= 0 && ts < LSEQ)
                    av = *(const float4*)(Ab + (size_t)ts * lda + ks + kc);
                alignas(8) unsigned short hs[4], ls[4];
                float fv[4] = {av.x, av.y, av.z, av.w};
#pragma unroll
                for (int j = 0; j < 4; ++j) {
                    unsigned short h = f2bf(fv[j]);
                    hs[j] = h;
                    ls[j] = f2bf(fv[j] - bf2f(h));
                }
                *(short4v*)&Ah[row][kc] = *(short4v*)hs;
                *(short4v*)&Al[row][kc] = *(short4v*)ls;
            }
            const int kglob = tap * Kd + ks;
#pragma unroll
            for (int l = 0; l < LB; ++l) {
                int c = tid + l * 256;
                int col = c >> 2, kc = (c & 3) << 3;
                size_t src = (size_t)(n0 + col) * wrow + kglob + kc;
                *(short8*)&Bh[col][kc] = *(const short8*)&Wh[src];
                *(short8*)&Bl[col][kc] = *(const short8*)&Wl[src];
            }
            __syncthreads();
            bf16x8 bhf[NR], blf[NR];
#pragma unroll
            for (int n = 0; n < NR; ++n) {
                int colr = wc * WN + n * 16 + fr;
                bhf[n] = __builtin_bit_cast(bf16x8, *(const short8*)&Bh[colr][fq * 8]);
                blf[n] = __builtin_bit_cast(bf16x8, *(const short8*)&Bl[colr][fq * 8]);
            }
#pragma unroll
            for (int m = 0; m < MR; ++m) {
                int rowr = wr * WM + m * 16 + fr;
                bf16x8 ahf = __builtin_bit_cast(bf16x8, *(const short8*)&Ah[rowr][fq * 8]);
                bf16x8 alf = __builtin_bit_cast(bf16x8, *(const short8*)&Al[rowr][fq * 8]);
#pragma unroll
                for (int n = 0; n < NR; ++n) {
                    acc[m][n] = __builtin_amdgcn_mfma_f32_16x16x32_bf16(ahf, bhf[n], acc[m][n], 0, 0, 0);
                    acc[m][n] = __builtin_amdgcn_mfma_f32_16x16x32_bf16(ahf, blf[n], acc[m][n], 0, 0, 0);
                    acc[m][n] = __builtin_amdgcn_mfma_f32_16x16x32_bf16(alf, bhf[n], acc[m][n], 0, 0, 0);
                }
            }
            __syncthreads();
        }
    }

#pragma unroll
    for (int m = 0; m < MR; ++m) {
#pragma unroll
        for (int n = 0; n < NR; ++n) {
            int colg = n0 + wc * WN + n * 16 + fr;
            if (colg >= Ntot) continue;
#pragma unroll
            for (int r = 0; r < 4; ++r) {
                int t = t0 + wr * WM + m * 16 + fq * 4 + r;
                if (t >= LSEQ) continue;
                float v = acc[m][n][r];
                if (epi == 1) {
                    v += bias[colg];
                    float gg = bn[colg], bb = bn[bnN + colg];
                    float mm = bn[2 * bnN + colg], vv = bn[3 * bnN + colg];
                    v = (v - mm) * (gg / sqrtf(vv + 1e-5f)) + bb;
                    v = v > 0.f ? v : 0.f;
                } else if (epi == 2) {
                    v += bias[colg];
                    v = v > 0.f ? v : 0.f;
                }
                Cb[(size_t)t * ldc + colg] = v;
            }
        }
    }
}

template<int BM, int BN>
__global__ __launch_bounds__(256) void gemm_mfma(
    const float* __restrict__ A, int lda,
    const unsigned short* __restrict__ Wh, const unsigned short* __restrict__ Wl,
    int Ntot, int Kd, int KT, int pad,
    const float* __restrict__ bias, const float* __restrict__ bn, int bnN, int epi,
    float* __restrict__ C, int ldc)
{
    const int b = blockIdx.z;
    gemm_body<BM, BN>(A + (size_t)b * LSEQ * lda, lda, Wh, Wl, Ntot, Kd, KT, pad,
                      bias, bn, bnN, epi, C + (size_t)b * LSEQ * ldc, ldc,
                      blockIdx.y * BM, blockIdx.x * BN);
}

// three tap-convs (K=3/5/7) fused into one dispatch: blockIdx.x = branch
__global__ __launch_bounds__(256) void convtri_mfma(
    const float* __restrict__ A,
    const unsigned short* __restrict__ c3h, const unsigned short* __restrict__ c3l,
    const unsigned short* __restrict__ c5h, const unsigned short* __restrict__ c5l,
    const unsigned short* __restrict__ c7h, const unsigned short* __restrict__ c7l,
    const float* __restrict__ c3b, const float* __restrict__ c5b, const float* __restrict__ c7b,
    const float* __restrict__ bn3, const float* __restrict__ bn5, const float* __restrict__ bn7,
    float* __restrict__ C)
{
    const int br = blockIdx.x;
    const int b  = blockIdx.z;
    const int KT = 3 + 2 * br, pad = 1 + br;
    const unsigned short* Wh = (br == 0) ? c3h : (br == 1) ? c5h : c7h;
    const unsigned short* Wl = (br == 0) ? c3l : (br == 1) ? c5l : c7l;
    const float* bias = (br == 0) ? c3b : (br == 1) ? c5b : c7b;
    const float* bn   = (br == 0) ? bn3 : (br == 1) ? bn5 : bn7;
    gemm_body<64, 64>(A + (size_t)b * LSEQ * 128, 128, Wh, Wl, 64, 128, KT, pad,
                      bias, bn, 64, 1,
                      C + (size_t)b * LSEQ * 192 + br * 64, 192,
                      blockIdx.y * 64, 0);
}

// ---------------- layernorm (one wave per 128-dim row) ----------------
__global__ __launch_bounds__(256) void ln_kernel(
    const float* __restrict__ in, const float* __restrict__ g,
    const float* __restrict__ b2, float* __restrict__ out)
{
    int lane = threadIdx.x & 63;
    int wid  = threadIdx.x >> 6;
    int row = blockIdx.x * 4 + wid;
    if (row >= BLROWS) return;
    const float* rp = in + (size_t)row * 128;
    float v0 = rp[lane], v1 = rp[lane + 64];
    float s = v0 + v1;
#pragma unroll
    for (int o2 = 32; o2 > 0; o2 >>= 1) s += __shfl_xor(s, o2, 64);
    float mu = s * (1.f / 128.f);
    float d0 = v0 - mu, d1 = v1 - mu;
    float q = d0 * d0 + d1 * d1;
#pragma unroll
    for (int o2 = 32; o2 > 0; o2 >>= 1) q += __shfl_xor(q, o2, 64);
    float rs = 1.f / sqrtf(q * (1.f / 128.f) + 1e-5f);
    float* op = out + (size_t)row * 128;
    op[lane]      = d0 * rs * g[lane]      + b2[lane];
    op[lane + 64] = d1 * rs * g[lane + 64] + b2[lane + 64];
}

// ---------------- depthwise causal conv (K=4) + silu ----------------
__global__ __launch_bounds__(256) void mconv_kernel(
    const float* __restrict__ xz, const float* __restrict__ Wc,
    const float* __restrict__ bc, float* __restrict__ u)
{
    int idx = blockIdx.x * 256 + threadIdx.x;
    int c = idx & 255;
    int r = idx >> 8;
    if (r >= BLROWS) return;
    int t = r % LSEQ;
    const float* xs = xz + (size_t)r * 512 + c;
    float acc = bc[c];
    if (t >= 3) acc = fmaf(xs[-3 * 512], Wc[c * 4 + 0], acc);
    if (t >= 2) acc = fmaf(xs[-2 * 512], Wc[c * 4 + 1], acc);
    if (t >= 1) acc = fmaf(xs[-1 * 512], Wc[c * 4 + 2], acc);
    acc = fmaf(xs[0], Wc[c * 4 + 3], acc);
    u[(size_t)r * 256 + c] = silu_f(acc);
}

// ---------------- dt = softplus(dbl[:, :8] @ dt_W.T + dt_b) ----------------
__global__ __launch_bounds__(256) void dtk_kernel(
    const float* __restrict__ dbl, const float* __restrict__ dtW,
    const float* __restrict__ dtb, float* __restrict__ dtout)
{
    int idx = blockIdx.x * 256 + threadIdx.x;
    int c = idx & 255;
    int r = idx >> 8;
    if (r >= BLROWS) return;
    const float* dr = dbl + (size_t)r * 40;
    float a = dtb[c];
#pragma unroll
    for (int j = 0; j < 8; ++j) a = fmaf(dr[j], dtW[c * 8 + j], a);
    float sp = (a > 20.f) ? a : log1pf(__expf(a));
    dtout[(size_t)r * 256 + c] = sp;
}

// ---------------- selective scan: 3-pass, 4 states per thread ----------------
// idx -> ng (state group, 4 states) | d | ch | b ; 16*27*1024 threads
__global__ __launch_bounds__(256) void scan1_kernel(
    const float* __restrict__ dt, const float* __restrict__ u,
    const float* __restrict__ dbl, const float* __restrict__ Alog,
    float* __restrict__ P, float* __restrict__ S)
{
    int idx = blockIdx.x * 256 + threadIdx.x;
    int ng = idx & 3;
    int d  = (idx >> 2) & 255;
    int rest = idx >> 10;
    int ch = rest % CHN;
    int b  = rest / CHN;
    int n0 = ng * 4;
    float A2[4];
#pragma unroll
    for (int j = 0; j < 4; ++j) A2[j] = -__expf(Alog[d * 16 + n0 + j]);
    float p[4] = {1.f, 1.f, 1.f, 1.f}, s[4] = {0.f, 0.f, 0.f, 0.f};
    int r0 = b * LSEQ + ch * LCH;
    for (int q = 0; q < LCH; ++q) {
        size_t r = (size_t)(r0 + q);
        float dtv = dt[r * 256 + d];
        float uv  = u [r * 256 + d];
        float dtu = dtv * uv;
        float4 Br = *(const float4*)(dbl + r * 40 + 8 + n0);
        float bv[4] = {Br.x, Br.y, Br.z, Br.w};
#pragma unroll
        for (int j = 0; j < 4; ++j) {
            float a = __expf(dtv * A2[j]);
            p[j] *= a;
            s[j] = fmaf(a, s[j], dtu * bv[j]);
        }
    }
    size_t ob = ((size_t)(b * CHN + ch) * 256 + d) * 16 + n0;
    *(float4*)&P[ob] = make_float4(p[0], p[1], p[2], p[3]);
    *(float4*)&S[ob] = make_float4(s[0], s[1], s[2], s[3]);
}

__global__ __launch_bounds__(256) void scan2_kernel(
    const float* __restrict__ P, const float* __restrict__ S, float* __restrict__ H0)
{
    int idx = blockIdx.x * 256 + threadIdx.x;   // 65536 = 16*256*16
    int n = idx & 15;
    int d = (idx >> 4) & 255;
    int b = idx >> 12;
    float h = 0.f;
    for (int ch = 0; ch < CHN; ++ch) {
        size_t o = ((size_t)(b * CHN + ch) * 256 + d) * 16 + n;
        H0[o] = h;
        h = fmaf(P[o], h, S[o]);
    }
}

__global__ __launch_bounds__(256) void scan3_kernel(
    const float* __restrict__ dt, const float* __restrict__ u,
    const float* __restrict__ dbl, const float* __restrict__ Alog,
    const float* __restrict__ H0, const float* __restrict__ Dp,
    const float* __restrict__ xz, float* __restrict__ g)
{
    int idx = blockIdx.x * 256 + threadIdx.x;
    int ng = idx & 3;
    int d  = (idx >> 2) & 255;
    int rest = idx >> 10;
    int ch = rest % CHN;
    int b  = rest / CHN;
    int n0 = ng * 4;
    float A2[4];
#pragma unroll
    for (int j = 0; j < 4; ++j) A2[j] = -__expf(Alog[d * 16 + n0 + j]);
    size_t ob = ((size_t)(b * CHN + ch) * 256 + d) * 16 + n0;
    float4 h4 = *(const float4*)&H0[ob];
    float h[4] = {h4.x, h4.y, h4.z, h4.w};
    float Dpd = Dp[d];
    int r0 = b * LSEQ + ch * LCH;
    for (int q = 0; q < LCH; ++q) {
        size_t r = (size_t)(r0 + q);
        float dtv = dt[r * 256 + d];
        float uv  = u [r * 256 + d];
        float dtu = dtv * uv;
        float4 Br = *(const float4*)(dbl + r * 40 + 8 + n0);
        float4 Cr = *(const float4*)(dbl + r * 40 + 24 + n0);
        float bv[4] = {Br.x, Br.y, Br.z, Br.w};
        float cv[4] = {Cr.x, Cr.y, Cr.z, Cr.w};
        float pacc = 0.f;
#pragma unroll
        for (int j = 0; j < 4; ++j) {
            float a = __expf(dtv * A2[j]);
            h[j] = fmaf(a, h[j], dtu * bv[j]);
            pacc = fmaf(h[j], cv[j], pacc);
        }
        float acc = pacc + __shfl_xor(pacc, 1);
        acc += __shfl_xor(acc, 2);
        if (ng == 0) {
            float yv = fmaf(uv, Dpd, acc);
            float zv = xz[r * 512 + 256 + d];
            g[r * 256 + d] = yv * silu_f(zv);
        }
    }
}

// ---------------- mean pool + final fc ----------------
__global__ __launch_bounds__(128) void pool1_kernel(
    const float* __restrict__ fused, float* __restrict__ part)
{
    int d = threadIdx.x;
    int blk = blockIdx.x;
    int ch = blk % CHN;
    int b  = blk / CHN;
    int t0 = ch * LCH;
    float s = 0.f;
    for (int q = 0; q < LCH; ++q)
        s += fused[((size_t)(b * LSEQ + t0 + q)) * 128 + d];
    part[(size_t)(b * CHN + ch) * 128 + d] = s;
}

__global__ __launch_bounds__(128) void pool2_kernel(
    const float* __restrict__ part, const float* __restrict__ fcW,
    const float* __restrict__ fcb, float* __restrict__ out)
{
    __shared__ float pl[128];
    int d = threadIdx.x;
    int b = blockIdx.x;
    float s = 0.f;
    for (int ch = 0; ch < CHN; ++ch) s += part[(size_t)(b * CHN + ch) * 128 + d];
    pl[d] = s * (1.f / 1080.f);
    __syncthreads();
    if (d < 3) {
        float a = fcb[d];
        for (int dd = 0; dd < 128; ++dd) a = fmaf(pl[dd], fcW[d * 128 + dd], a);
        out[b * 3 + d] = a;
    }
}

// ---------------- host orchestration ----------------
extern "C" void kernel_launch(void* const* d_in, const int* in_sizes, int n_in,
                              void* d_out, int out_size, void* d_ws, size_t ws_size,
                              hipStream_t stream)
{
    const float* x    = (const float*)d_in[0];
    const float* embW = (const float*)d_in[1];
    const float* embb = (const float*)d_in[2];
    const float* c3W  = (const float*)d_in[3];
    const float* c3b  = (const float*)d_in[4];
    const float* bn3  = (const float*)d_in[5];
    const float* c5W  = (const float*)d_in[6];
    const float* c5b  = (const float*)d_in[7];
    const float* bn5  = (const float*)d_in[8];
    const float* c7W  = (const float*)d_in[9];
    const float* c7b  = (const float*)d_in[10];
    const float* bn7  = (const float*)d_in[11];
    const float* cfW  = (const float*)d_in[12];
    const float* cfb  = (const float*)d_in[13];
    const float* bnf  = (const float*)d_in[14];
    const float* lng  = (const float*)d_in[15];
    const float* lnb  = (const float*)d_in[16];
    const float* inW  = (const float*)d_in[17];
    const float* mcW  = (const float*)d_in[18];
    const float* mcb  = (const float*)d_in[19];
    const float* xpW  = (const float*)d_in[20];
    const float* dtW  = (const float*)d_in[21];
    const float* dtbp = (const float*)d_in[22];
    const float* Alog = (const float*)d_in[23];
    const float* Dp   = (const float*)d_in[24];
    const float* outW = (const float*)d_in[25];
    const float* flW  = (const float*)d_in[26];
    const float* flb  = (const float*)d_in[27];
    const float* fcW  = (const float*)d_in[28];
    const float* fcb  = (const float*)d_in[29];

    float* ws = (float*)d_ws;
    size_t off = 0;
    auto alloc = [&](size_t n) { float* p = ws + off; off += n; return p; };
    float* xe   = alloc((size_t)BLROWS * 128);
    float* lnx  = alloc((size_t)BLROWS * 128);   // reused later as 'fused'
    float* xz   = alloc((size_t)BLROWS * 512);
    float* ub   = alloc((size_t)BLROWS * 256);
    float* dtt  = alloc((size_t)BLROWS * 256);
    float* dbl  = alloc((size_t)BLROWS * 40);
    float* gb   = alloc((size_t)BLROWS * 256);   // first 192 cols double as 'cc'
    float* mbuf = alloc((size_t)BLROWS * 128);
    float* fin  = alloc((size_t)BLROWS * 256);
    float* Pb   = alloc((size_t)NBATCH * CHN * 256 * 16);  // reused as pool partials
    float* Sb   = alloc((size_t)NBATCH * CHN * 256 * 16);
    float* h0b  = alloc((size_t)NBATCH * CHN * 256 * 16);
    float* cc    = gb;
    float* fused = lnx;

    off = (off + 3) & ~(size_t)3;
    unsigned short* us = (unsigned short*)(ws + off);
    size_t uo = 0;
    auto ualloc = [&](size_t n) { unsigned short* p = us + uo; uo += n; return p; };
    unsigned short* c3h = ualloc(64 * 384);  unsigned short* c3l = ualloc(64 * 384);
    unsigned short* c5h = ualloc(64 * 640);  unsigned short* c5l = ualloc(64 * 640);
    unsigned short* c7h = ualloc(64 * 896);  unsigned short* c7l = ualloc(64 * 896);
    unsigned short* cfh = ualloc(128 * 192); unsigned short* cfl = ualloc(128 * 192);
    unsigned short* inh = ualloc((size_t)1536 * 128); unsigned short* inl = ualloc((size_t)1536 * 128);
    unsigned short* xph = ualloc((size_t)3 * 64 * 256); unsigned short* xpl = ualloc((size_t)3 * 64 * 256);
    unsigned short* oth = ualloc((size_t)384 * 256); unsigned short* otl = ualloc((size_t)384 * 256);
    unsigned short* flh = ualloc((size_t)128 * 256); unsigned short* fll = ualloc((size_t)128 * 256);
    (void)ws_size; (void)in_sizes; (void)n_in; (void)out_size;

    // 0. all weight conversions in one launch
    convw_all<<<2048, 256, 0, stream>>>(c3W, c5W, c7W, cfW, inW, xpW, outW, flW,
                                        c3h, c3l, c5h, c5l, c7h, c7l, cfh, cfl,
                                        inh, inl, xph, xpl, oth, otl, flh, fll);

    // 1. embedding + positional encoding
    embed_kernel<<<(BLROWS * 128) / 256, 256, 0, stream>>>(x, embW, embb, xe);

    // 2. CNN branch: fused 3-conv dispatch, then 1x1 fuse
    dim3 gtri(3, 17, NBATCH);
    convtri_mfma<<<gtri, 256, 0, stream>>>(xe, c3h, c3l, c5h, c5l, c7h, c7l,
                                           c3b, c5b, c7b, bn3, bn5, bn7, cc);
    dim3 g64(1, 17, NBATCH);
    dim3 g128(1, 17, NBATCH);
    gemm_mfma<64, 128><<<g128, 256, 0, stream>>>(cc, 192, cfh, cfl, 128, 192, 1, 0,
                                                 cfb, bnf, 128, 1, fin, 256);

    // 3. three mamba blocks
    for (int i = 0; i < 3; ++i) {
        const float* min_ = (i == 0) ? xe : ((i == 1) ? mbuf : xe);
        float* mout = (i == 0) ? mbuf : ((i == 1) ? xe : (fin + 128));
        int ldout = (i < 2) ? 128 : 256;

        ln_kernel<<<BLROWS / 4, 256, 0, stream>>>(min_, lng + i * 128, lnb + i * 128, lnx);

        dim3 gin(4, 17, NBATCH);
        gemm_mfma<64, 128><<<gin, 256, 0, stream>>>(lnx, 128, inh + (size_t)i * 512 * 128,
                                                    inl + (size_t)i * 512 * 128,
                                                    512, 128, 1, 0, nullptr, nullptr, 0, 0,
                                                    xz, 512);

        mconv_kernel<<<BLROWS, 256, 0, stream>>>(xz, mcW + i * 256 * 4, mcb + i * 256, ub);

        gemm_mfma<64, 64><<<g64, 256, 0, stream>>>(ub, 256, xph + (size_t)i * 64 * 256,
                                                   xpl + (size_t)i * 64 * 256,
                                                   40, 256, 1, 0, nullptr, nullptr, 0, 0,
                                                   dbl, 40);

        dtk_kernel<<<BLROWS, 256, 0, stream>>>(dbl, dtW + i * 256 * 8, dtbp + i * 256, dtt);

        scan1_kernel<<<(NBATCH * CHN * 1024) / 256, 256, 0, stream>>>(
            dtt, ub, dbl, Alog + i * 256 * 16, Pb, Sb);
        scan2_kernel<<<(NBATCH * 256 * 16) / 256, 256, 0, stream>>>(Pb, Sb, h0b);
        scan3_kernel<<<(NBATCH * CHN * 1024) / 256, 256, 0, stream>>>(
            dtt, ub, dbl, Alog + i * 256 * 16, h0b, Dp + i * 256, xz, gb);

        gemm_mfma<64, 128><<<g128, 256, 0, stream>>>(gb, 256, oth + (size_t)i * 128 * 256,
                                                     otl + (size_t)i * 128 * 256,
                                                     128, 256, 1, 0, nullptr, nullptr, 0, 0,
                                                     mout, ldout);
    }

    // 4. fusion linear + relu
    gemm_mfma<64, 128><<<g128, 256, 0, stream>>>(fin, 256, flh, fll, 128, 256, 1, 0,
                                                 flb, nullptr, 0, 2, fused, 128);

    // 5. mean pool + final fc
    pool1_kernel<<<NBATCH * CHN, 128, 0, stream>>>(fused, Pb);
    pool2_kernel<<<NBATCH, 128, 0, stream>>>(Pb, fcW, fcb, (float*)d_out);
}

// Round 4
// 680.429 us; speedup vs baseline: 1.8336x; 1.0023x over previous
//
#include <hip/hip_runtime.h>
#include <math.h>

#define LSEQ   1080
#define NBATCH 16
#define BLROWS (LSEQ*NBATCH)   // 17280
#define CHN    27
#define LCH    40              // 27*40 = 1080

typedef __bf16  bf16x8 __attribute__((ext_vector_type(8)));
typedef float   f32x4  __attribute__((ext_vector_type(4)));
typedef short   short8 __attribute__((ext_vector_type(8)));
typedef short   short4v __attribute__((ext_vector_type(4)));

__device__ __forceinline__ float silu_f(float x) { return x / (1.f + __expf(-x)); }

__device__ __forceinline__ unsigned short f2bf(float f) {
    unsigned int u = __float_as_uint(f);
    u += 0x7fffu + ((u >> 16) & 1u);
    return (unsigned short)(u >> 16);
}
__device__ __forceinline__ float bf2f(unsigned short h) {
    return __uint_as_float(((unsigned int)h) << 16);
}
__device__ __forceinline__ void split_bf(float v, unsigned short& h, unsigned short& l) {
    h = f2bf(v);
    l = f2bf(v - bf2f(h));
}

// ---------------- embed + positional encoding ----------------
__global__ __launch_bounds__(256) void embed_kernel(
    const float* __restrict__ x, const float* __restrict__ embW,
    const float* __restrict__ embb, float* __restrict__ xe)
{
    int idx = blockIdx.x * 256 + threadIdx.x;
    if (idx >= BLROWS * 128) return;
    int d = idx & 127;
    int r = idx >> 7;
    int t = r % LSEQ;
    float x0 = x[(size_t)r * 2], x1 = x[(size_t)r * 2 + 1];
    int i2 = d & 126;
    float div = expf((float)i2 * (-9.210340371976184f / 128.f));
    float arg = (float)t * div;
    float pe = (d & 1) ? cosf(arg) : sinf(arg);
    xe[idx] = fmaf(x0, embW[d], fmaf(x1, embW[128 + d], embb[d] + pe));
}

// ---------------- all weight conversions + scale/shift packing --------------
// jobs: w192 [192][896] tap-aligned zero-padded | cf | in | xp(padded) | ot | fl | scsh
#define JOB_W192  172032
#define JOB_CF    196608
#define JOB_IN    393216
#define JOB_XP    442368
#define JOB_OT    540672
#define JOB_FL    573440
#define JOB_END   574080
__global__ __launch_bounds__(256) void convw_all(
    const float* __restrict__ c3W, const float* __restrict__ c5W,
    const float* __restrict__ c7W, const float* __restrict__ cfW,
    const float* __restrict__ inW, const float* __restrict__ xpW,
    const float* __restrict__ otW, const float* __restrict__ flW,
    const float* __restrict__ c3b, const float* __restrict__ c5b, const float* __restrict__ c7b,
    const float* __restrict__ bn3, const float* __restrict__ bn5, const float* __restrict__ bn7,
    const float* __restrict__ cfb, const float* __restrict__ bnf,
    unsigned short* __restrict__ w192h, unsigned short* __restrict__ w192l,
    unsigned short* __restrict__ cfh, unsigned short* __restrict__ cfl,
    unsigned short* __restrict__ inh, unsigned short* __restrict__ inl,
    unsigned short* __restrict__ xph, unsigned short* __restrict__ xpl,
    unsigned short* __restrict__ oth, unsigned short* __restrict__ otl,
    unsigned short* __restrict__ flh, unsigned short* __restrict__ fll,
    float* __restrict__ schpack)
{
    int idx = blockIdx.x * 256 + threadIdx.x;
    if (idx >= JOB_END) return;
    if (idx >= JOB_FL + 32768) { return; }
    float v;
    unsigned short *dh, *dl;
    int off;
    if (idx < JOB_W192) {
        off = idx;
        int n = off / 896, kk = off % 896;
        int slot = kk >> 7, d = kk & 127;
        int br = n >> 6, c = n & 63;
        int KT = 3 + 2 * br, pad = 1 + br;
        int tp = slot - 3 + pad;
        const float* w = (br == 0) ? c3W : (br == 1) ? c5W : c7W;
        v = (tp >= 0 && tp < KT) ? w[((c << 7) + d) * KT + tp] : 0.f;
        dh = w192h; dl = w192l;
    } else if (idx < JOB_CF) {
        off = idx - JOB_W192; v = cfW[off]; dh = cfh; dl = cfl;
    } else if (idx < JOB_IN) {
        off = idx - JOB_CF; v = inW[off]; dh = inh; dl = inl;
    } else if (idx < JOB_XP) {
        off = idx - JOB_IN;
        int k = off & 255, n = (off >> 8) & 63, blk = off >> 14;
        v = (n < 40) ? xpW[((size_t)blk * 40 + n) * 256 + k] : 0.f;
        dh = xph; dl = xpl;
    } else if (idx < JOB_OT) {
        off = idx - JOB_XP; v = otW[off]; dh = oth; dl = otl;
    } else if (idx < JOB_FL) {
        off = idx - JOB_OT; v = flW[off]; dh = flh; dl = fll;
    } else {
        int j = idx - JOB_FL;
        if (j < 384) {
            int col = (j < 192) ? j : j - 192;
            int isSh = j >= 192;
            int br = col >> 6, c = col & 63;
            const float* bn = (br == 0) ? bn3 : (br == 1) ? bn5 : bn7;
            float bias = ((br == 0) ? c3b : (br == 1) ? c5b : c7b)[c];
            float g = bn[c], bb = bn[64 + c], m = bn[128 + c], vv = bn[192 + c];
            float scale = g * rsqrtf(vv + 1e-5f);
            float shift = (bias - m) * scale + bb;
            schpack[j] = isSh ? shift : scale;
        } else {
            int j2 = j - 384;
            int col = j2 & 127;
            int isSh = j2 >= 128;
            float g = bnf[col], bb = bnf[128 + col], m = bnf[256 + col], vv = bnf[384 + col];
            float scale = g * rsqrtf(vv + 1e-5f);
            float shift = (cfb[col] - m) * scale + bb;
            schpack[384 + j2] = isSh ? shift : scale;
        }
        return;
    }
    unsigned short h, l;
    split_bf(v, h, l);
    dh[off] = h; dl[off] = l;
}

// ---------------- CNN front-end: halo GEMM over unified 7-tap weights -------
// out cc[t, n0+n] = relu( (sum_{tap,d} xe[t+tap-3,d]*w192[n][tap*128+d]) *sc+sh )
__global__ __launch_bounds__(256) void gemm_conv(
    const float* __restrict__ xe,
    const unsigned short* __restrict__ Wh, const unsigned short* __restrict__ Wl,
    const float* __restrict__ sc, const float* __restrict__ sh,
    unsigned short* __restrict__ Ch, unsigned short* __restrict__ Cl)
{
    __shared__ unsigned short Ah[70][40], Al[70][40];
    __shared__ unsigned short Bh[64][136], Bl[64][136];
    const int tid = threadIdx.x;
    const int n0 = blockIdx.x * 64, t0 = blockIdx.y * 64, b = blockIdx.z;
    const float* Ab = xe + (size_t)b * LSEQ * 128;
    const int lane = tid & 63, wid = tid >> 6;
    const int wr = wid >> 1, wc = wid & 1;
    const int fr = lane & 15, fq = lane >> 4;
    f32x4 acc[2][2];
#pragma unroll
    for (int m = 0; m < 2; ++m)
#pragma unroll
        for (int n = 0; n < 2; ++n) acc[m][n] = (f32x4){0.f, 0.f, 0.f, 0.f};

    for (int ks = 0; ks < 128; ks += 32) {
        // stage A halo: rows t0-3 .. t0+66, 32 k
#pragma unroll
        for (int l = 0; l < 3; ++l) {
            int c = tid + l * 256;
            if (c < 560) {
                int row = c >> 3, kq = (c & 7) << 2;
                int ts = t0 - 3 + row;
                float4 av = make_float4(0.f, 0.f, 0.f, 0.f);
                if (ts >= 0 && ts < LSEQ)
                    av = *(const float4*)(Ab + (size_t)ts * 128 + ks + kq);
                alignas(8) unsigned short hs[4], ls[4];
                float fv[4] = {av.x, av.y, av.z, av.w};
#pragma unroll
                for (int j = 0; j < 4; ++j) split_bf(fv[j], hs[j], ls[j]);
                *(short4v*)&Ah[row][kq] = *(short4v*)hs;
                *(short4v*)&Al[row][kq] = *(short4v*)ls;
            }
        }
        for (int g = 0; g < 2; ++g) {
            const int ntap = (g == 0) ? 4 : 3;
            // stage B: 64 cols x ntap taps x 32 k
#pragma unroll
            for (int l = 0; l < 4; ++l) {
                int c = tid + l * 256;
                int col = c >> 4, rem = c & 15, tt = rem >> 2, kq = (rem & 3) << 3;
                if (tt < ntap) {
                    int tap = g * 4 + tt;
                    size_t s = (size_t)(n0 + col) * 896 + tap * 128 + ks + kq;
                    *(short8*)&Bh[col][tt * 32 + kq] = *(const short8*)&Wh[s];
                    *(short8*)&Bl[col][tt * 32 + kq] = *(const short8*)&Wl[s];
                }
            }
            __syncthreads();
            for (int tt = 0; tt < ntap; ++tt) {
                int tap = g * 4 + tt;
                bf16x8 bhf[2], blf[2];
#pragma unroll
                for (int n = 0; n < 2; ++n) {
                    int col = wc * 32 + n * 16 + fr;
                    bhf[n] = __builtin_bit_cast(bf16x8, *(const short8*)&Bh[col][tt * 32 + fq * 8]);
                    blf[n] = __builtin_bit_cast(bf16x8, *(const short8*)&Bl[col][tt * 32 + fq * 8]);
                }
#pragma unroll
                for (int m = 0; m < 2; ++m) {
                    int rowA = wr * 32 + m * 16 + fr + tap;
                    bf16x8 ahf = __builtin_bit_cast(bf16x8, *(const short8*)&Ah[rowA][fq * 8]);
                    bf16x8 alf = __builtin_bit_cast(bf16x8, *(const short8*)&Al[rowA][fq * 8]);
#pragma unroll
                    for (int n = 0; n < 2; ++n) {
                        acc[m][n] = __builtin_amdgcn_mfma_f32_16x16x32_bf16(ahf, bhf[n], acc[m][n], 0, 0, 0);
                        acc[m][n] = __builtin_amdgcn_mfma_f32_16x16x32_bf16(ahf, blf[n], acc[m][n], 0, 0, 0);
                        acc[m][n] = __builtin_amdgcn_mfma_f32_16x16x32_bf16(alf, bhf[n], acc[m][n], 0, 0, 0);
                    }
                }
            }
            __syncthreads();
        }
    }
    // epilogue: relu(acc*sc+sh) -> hi/lo
    unsigned short* Chb = Ch + (size_t)b * LSEQ * 192;
    unsigned short* Clb = Cl + (size_t)b * LSEQ * 192;
#pragma unroll
    for (int m = 0; m < 2; ++m) {
#pragma unroll
        for (int n = 0; n < 2; ++n) {
            int colg = n0 + wc * 32 + n * 16 + fr;
            float scl = sc[colg], shf2 = sh[colg];
#pragma unroll
            for (int r = 0; r < 4; ++r) {
                int t = t0 + wr * 32 + m * 16 + fq * 4 + r;
                if (t >= LSEQ) continue;
                float v = fmaf(acc[m][n][r], scl, shf2);
                v = v > 0.f ? v : 0.f;
                unsigned short h, l;
                split_bf(v, h, l);
                Chb[(size_t)t * 192 + colg] = h;
                Clb[(size_t)t * 192 + colg] = l;
            }
        }
    }
}

// ---------------- generic MFMA GEMM, pre-split A and W ----------------------
// epi: 0 = plain fp32 | 1 = relu(v*sc+sh) -> hi/lo | 2 = relu(v+bias) fp32 | 3 = plain hi/lo
template<int BM, int BN>
__global__ __launch_bounds__(256) void gemm_plain(
    const unsigned short* __restrict__ Aph, const unsigned short* __restrict__ Apl, int lda,
    const unsigned short* __restrict__ Wh, const unsigned short* __restrict__ Wl, int Kd,
    int Ntot, int epi,
    const float* __restrict__ sc, const float* __restrict__ sh, const float* __restrict__ bias,
    float* __restrict__ Cf, int ldc,
    unsigned short* __restrict__ Ch, unsigned short* __restrict__ Cl, int ldch)
{
    constexpr int WM = BM / 2, WN = BN / 2;
    constexpr int MR = WM / 16, NR = WN / 16;
    constexpr int ACH = (BM * 4) / 256;
    constexpr int BCH = (BN * 4) / 256;
    __shared__ unsigned short Ah[BM][40], Al[BM][40];
    __shared__ unsigned short Bh[BN][40], Bl[BN][40];
    const int tid = threadIdx.x;
    const int b = blockIdx.z, t0 = blockIdx.y * BM, n0 = blockIdx.x * BN;
    const unsigned short* Abh = Aph + (size_t)b * LSEQ * lda;
    const unsigned short* Abl = Apl + (size_t)b * LSEQ * lda;
    const int lane = tid & 63, wid = tid >> 6;
    const int wr = wid >> 1, wc = wid & 1;
    const int fr = lane & 15, fq = lane >> 4;
    f32x4 acc[MR][NR];
#pragma unroll
    for (int m = 0; m < MR; ++m)
#pragma unroll
        for (int n = 0; n < NR; ++n) acc[m][n] = (f32x4){0.f, 0.f, 0.f, 0.f};

    const short8 zz = {0, 0, 0, 0, 0, 0, 0, 0};
    for (int ks = 0; ks < Kd; ks += 32) {
#pragma unroll
        for (int l = 0; l < ACH; ++l) {
            int c = tid + l * 256;
            int row = c >> 2, kc = (c & 3) << 3;
            int t = t0 + row;
            short8 vh = zz, vl = zz;
            if (t < LSEQ) {
                size_t s = (size_t)t * lda + ks + kc;
                vh = *(const short8*)&Abh[s];
                vl = *(const short8*)&Abl[s];
            }
            *(short8*)&Ah[row][kc] = vh;
            *(short8*)&Al[row][kc] = vl;
        }
#pragma unroll
        for (int l = 0; l < BCH; ++l) {
            int c = tid + l * 256;
            int col = c >> 2, kc = (c & 3) << 3;
            size_t s = (size_t)(n0 + col) * Kd + ks + kc;
            *(short8*)&Bh[col][kc] = *(const short8*)&Wh[s];
            *(short8*)&Bl[col][kc] = *(const short8*)&Wl[s];
        }
        __syncthreads();
        bf16x8 bhf[NR], blf[NR];
#pragma unroll
        for (int n = 0; n < NR; ++n) {
            int col = wc * WN + n * 16 + fr;
            bhf[n] = __builtin_bit_cast(bf16x8, *(const short8*)&Bh[col][fq * 8]);
            blf[n] = __builtin_bit_cast(bf16x8, *(const short8*)&Bl[col][fq * 8]);
        }
#pragma unroll
        for (int m = 0; m < MR; ++m) {
            int rowr = wr * WM + m * 16 + fr;
            bf16x8 ahf = __builtin_bit_cast(bf16x8, *(const short8*)&Ah[rowr][fq * 8]);
            bf16x8 alf = __builtin_bit_cast(bf16x8, *(const short8*)&Al[rowr][fq * 8]);
#pragma unroll
            for (int n = 0; n < NR; ++n) {
                acc[m][n] = __builtin_amdgcn_mfma_f32_16x16x32_bf16(ahf, bhf[n], acc[m][n], 0, 0, 0);
                acc[m][n] = __builtin_amdgcn_mfma_f32_16x16x32_bf16(ahf, blf[n], acc[m][n], 0, 0, 0);
                acc[m][n] = __builtin_amdgcn_mfma_f32_16x16x32_bf16(alf, bhf[n], acc[m][n], 0, 0, 0);
            }
        }
        __syncthreads();
    }

    float* Cfb = Cf ? Cf + (size_t)b * LSEQ * ldc : nullptr;
    unsigned short* Chb = Ch ? Ch + (size_t)b * LSEQ * ldch : nullptr;
    unsigned short* Clb = Cl ? Cl + (size_t)b * LSEQ * ldch : nullptr;
#pragma unroll
    for (int m = 0; m < MR; ++m) {
#pragma unroll
        for (int n = 0; n < NR; ++n) {
            int colg = n0 + wc * WN + n * 16 + fr;
            if (colg >= Ntot) continue;
#pragma unroll
            for (int r = 0; r < 4; ++r) {
                int t = t0 + wr * WM + m * 16 + fq * 4 + r;
                if (t >= LSEQ) continue;
                float v = acc[m][n][r];
                if (epi == 0) {
                    Cfb[(size_t)t * ldc + colg] = v;
                } else if (epi == 1) {
                    v = fmaf(v, sc[colg], sh[colg]);
                    v = v > 0.f ? v : 0.f;
                    unsigned short h, l;
                    split_bf(v, h, l);
                    Chb[(size_t)t * ldch + colg] = h;
                    Clb[(size_t)t * ldch + colg] = l;
                } else if (epi == 2) {
                    v += bias[colg];
                    v = v > 0.f ? v : 0.f;
                    Cfb[(size_t)t * ldc + colg] = v;
                } else {
                    unsigned short h, l;
                    split_bf(v, h, l);
                    Chb[(size_t)t * ldch + colg] = h;
                    Clb[(size_t)t * ldch + colg] = l;
                }
            }
        }
    }
}

// ---------------- layernorm -> hi/lo bf16 ----------------
__global__ __launch_bounds__(256) void ln_kernel(
    const float* __restrict__ in, const float* __restrict__ g,
    const float* __restrict__ b2, unsigned short* __restrict__ oh,
    unsigned short* __restrict__ ol)
{
    int lane = threadIdx.x & 63;
    int wid  = threadIdx.x >> 6;
    int row = blockIdx.x * 4 + wid;
    if (row >= BLROWS) return;
    const float* rp = in + (size_t)row * 128;
    float v0 = rp[lane], v1 = rp[lane + 64];
    float s = v0 + v1;
#pragma unroll
    for (int o2 = 32; o2 > 0; o2 >>= 1) s += __shfl_xor(s, o2, 64);
    float mu = s * (1.f / 128.f);
    float d0 = v0 - mu, d1 = v1 - mu;
    float q = d0 * d0 + d1 * d1;
#pragma unroll
    for (int o2 = 32; o2 > 0; o2 >>= 1) q += __shfl_xor(q, o2, 64);
    float rs = 1.f / sqrtf(q * (1.f / 128.f) + 1e-5f);
    float y0 = d0 * rs * g[lane]      + b2[lane];
    float y1 = d1 * rs * g[lane + 64] + b2[lane + 64];
    unsigned short h, l;
    size_t o = (size_t)row * 128;
    split_bf(y0, h, l); oh[o + lane] = h;      ol[o + lane] = l;
    split_bf(y1, h, l); oh[o + lane + 64] = h; ol[o + lane + 64] = l;
}

// ---------------- depthwise causal conv (K=4) + silu -> fp32 + hi/lo --------
__global__ __launch_bounds__(256) void mconv_kernel(
    const float* __restrict__ xz, const float* __restrict__ Wc,
    const float* __restrict__ bc, float* __restrict__ u,
    unsigned short* __restrict__ uh, unsigned short* __restrict__ ul)
{
    int idx = blockIdx.x * 256 + threadIdx.x;
    int c = idx & 255;
    int r = idx >> 8;
    if (r >= BLROWS) return;
    int t = r % LSEQ;
    const float* xs = xz + (size_t)r * 512 + c;
    float acc = bc[c];
    if (t >= 3) acc = fmaf(xs[-3 * 512], Wc[c * 4 + 0], acc);
    if (t >= 2) acc = fmaf(xs[-2 * 512], Wc[c * 4 + 1], acc);
    if (t >= 1) acc = fmaf(xs[-1 * 512], Wc[c * 4 + 2], acc);
    acc = fmaf(xs[0], Wc[c * 4 + 3], acc);
    float uv = silu_f(acc);
    size_t o = (size_t)r * 256 + c;
    u[o] = uv;
    unsigned short h, l;
    split_bf(uv, h, l);
    uh[o] = h; ul[o] = l;
}

// ---------------- dt = softplus(dbl[:, :8] @ dt_W.T + dt_b) ----------------
__global__ __launch_bounds__(256) void dtk_kernel(
    const float* __restrict__ dbl, const float* __restrict__ dtW,
    const float* __restrict__ dtb, float* __restrict__ dtout)
{
    int idx = blockIdx.x * 256 + threadIdx.x;
    int c = idx & 255;
    int r = idx >> 8;
    if (r >= BLROWS) return;
    const float* dr = dbl + (size_t)r * 40;
    float a = dtb[c];
#pragma unroll
    for (int j = 0; j < 8; ++j) a = fmaf(dr[j], dtW[c * 8 + j], a);
    float sp = (a > 20.f) ? a : log1pf(__expf(a));
    dtout[(size_t)r * 256 + c] = sp;
}

// ---------------- selective scan: 3-pass, 4 states per thread ----------------
__global__ __launch_bounds__(256) void scan1_kernel(
    const float* __restrict__ dt, const float* __restrict__ u,
    const float* __restrict__ dbl, const float* __restrict__ Alog,
    float* __restrict__ P, float* __restrict__ S)
{
    int idx = blockIdx.x * 256 + threadIdx.x;
    int ng = idx & 3;
    int d  = (idx >> 2) & 255;
    int rest = idx >> 10;
    int ch = rest % CHN;
    int b  = rest / CHN;
    int n0 = ng * 4;
    float A2[4];
#pragma unroll
    for (int j = 0; j < 4; ++j) A2[j] = -__expf(Alog[d * 16 + n0 + j]);
    float p[4] = {1.f, 1.f, 1.f, 1.f}, s[4] = {0.f, 0.f, 0.f, 0.f};
    int r0 = b * LSEQ + ch * LCH;
    for (int q = 0; q < LCH; ++q) {
        size_t r = (size_t)(r0 + q);
        float dtv = dt[r * 256 + d];
        float uv  = u [r * 256 + d];
        float dtu = dtv * uv;
        float4 Br = *(const float4*)(dbl + r * 40 + 8 + n0);
        float bv[4] = {Br.x, Br.y, Br.z, Br.w};
#pragma unroll
        for (int j = 0; j < 4; ++j) {
            float a = __expf(dtv * A2[j]);
            p[j] *= a;
            s[j] = fmaf(a, s[j], dtu * bv[j]);
        }
    }
    size_t ob = ((size_t)(b * CHN + ch) * 256 + d) * 16 + n0;
    *(float4*)&P[ob] = make_float4(p[0], p[1], p[2], p[3]);
    *(float4*)&S[ob] = make_float4(s[0], s[1], s[2], s[3]);
}

__global__ __launch_bounds__(256) void scan2_kernel(
    const float* __restrict__ P, const float* __restrict__ S, float* __restrict__ H0)
{
    int idx = blockIdx.x * 256 + threadIdx.x;   // 65536 = 16*256*16
    int n = idx & 15;
    int d = (idx >> 4) & 255;
    int b = idx >> 12;
    float h = 0.f;
    for (int ch = 0; ch < CHN; ++ch) {
        size_t o = ((size_t)(b * CHN + ch) * 256 + d) * 16 + n;
        H0[o] = h;
        h = fmaf(P[o], h, S[o]);
    }
}

__global__ __launch_bounds__(256) void scan3_kernel(
    const float* __restrict__ dt, const float* __restrict__ u,
    const float* __restrict__ dbl, const float* __restrict__ Alog,
    const float* __restrict__ H0, const float* __restrict__ Dp,
    const float* __restrict__ xz, unsigned short* __restrict__ gh,
    unsigned short* __restrict__ gl)
{
    int idx = blockIdx.x * 256 + threadIdx.x;
    int ng = idx & 3;
    int d  = (idx >> 2) & 255;
    int rest = idx >> 10;
    int ch = rest % CHN;
    int b  = rest / CHN;
    int n0 = ng * 4;
    float A2[4];
#pragma unroll
    for (int j = 0; j < 4; ++j) A2[j] = -__expf(Alog[d * 16 + n0 + j]);
    size_t ob = ((size_t)(b * CHN + ch) * 256 + d) * 16 + n0;
    float4 h4 = *(const float4*)&H0[ob];
    float h[4] = {h4.x, h4.y, h4.z, h4.w};
    float Dpd = Dp[d];
    int r0 = b * LSEQ + ch * LCH;
    for (int q = 0; q < LCH; ++q) {
        size_t r = (size_t)(r0 + q);
        float dtv = dt[r * 256 + d];
        float uv  = u [r * 256 + d];
        float dtu = dtv * uv;
        float4 Br = *(const float4*)(dbl + r * 40 + 8 + n0);
        float4 Cr = *(const float4*)(dbl + r * 40 + 24 + n0);
        float bv[4] = {Br.x, Br.y, Br.z, Br.w};
        float cv[4] = {Cr.x, Cr.y, Cr.z, Cr.w};
        float pacc = 0.f;
#pragma unroll
        for (int j = 0; j < 4; ++j) {
            float a = __expf(dtv * A2[j]);
            h[j] = fmaf(a, h[j], dtu * bv[j]);
            pacc = fmaf(h[j], cv[j], pacc);
        }
        float acc = pacc + __shfl_xor(pacc, 1);
        acc += __shfl_xor(acc, 2);
        if (ng == 0) {
            float yv = fmaf(uv, Dpd, acc);
            float zv = xz[r * 512 + 256 + d];
            float gv = yv * silu_f(zv);
            unsigned short hh, ll;
            split_bf(gv, hh, ll);
            gh[r * 256 + d] = hh;
            gl[r * 256 + d] = ll;
        }
    }
}

// ---------------- mean pool + final fc ----------------
__global__ __launch_bounds__(128) void pool1_kernel(
    const float* __restrict__ fused, float* __restrict__ part)
{
    int d = threadIdx.x;
    int blk = blockIdx.x;
    int ch = blk % CHN;
    int b  = blk / CHN;
    int t0 = ch * LCH;
    float s = 0.f;
    for (int q = 0; q < LCH; ++q)
        s += fused[((size_t)(b * LSEQ + t0 + q)) * 128 + d];
    part[(size_t)(b * CHN + ch) * 128 + d] = s;
}

__global__ __launch_bounds__(128) void pool2_kernel(
    const float* __restrict__ part, const float* __restrict__ fcW,
    const float* __restrict__ fcb, float* __restrict__ out)
{
    __shared__ float pl[128];
    int d = threadIdx.x;
    int b = blockIdx.x;
    float s = 0.f;
    for (int ch = 0; ch < CHN; ++ch) s += part[(size_t)(b * CHN + ch) * 128 + d];
    pl[d] = s * (1.f / 1080.f);
    __syncthreads();
    if (d < 3) {
        float a = fcb[d];
        for (int dd = 0; dd < 128; ++dd) a = fmaf(pl[dd], fcW[d * 128 + dd], a);
        out[b * 3 + d] = a;
    }
}

// ---------------- host orchestration ----------------
extern "C" void kernel_launch(void* const* d_in, const int* in_sizes, int n_in,
                              void* d_out, int out_size, void* d_ws, size_t ws_size,
                              hipStream_t stream)
{
    const float* x    = (const float*)d_in[0];
    const float* embW = (const float*)d_in[1];
    const float* embb = (const float*)d_in[2];
    const float* c3W  = (const float*)d_in[3];
    const float* c3b  = (const float*)d_in[4];
    const float* bn3  = (const float*)d_in[5];
    const float* c5W  = (const float*)d_in[6];
    const float* c5b  = (const float*)d_in[7];
    const float* bn5  = (const float*)d_in[8];
    const float* c7W  = (const float*)d_in[9];
    const float* c7b  = (const float*)d_in[10];
    const float* bn7  = (const float*)d_in[11];
    const float* cfW  = (const float*)d_in[12];
    const float* cfb  = (const float*)d_in[13];
    const float* bnf  = (const float*)d_in[14];
    const float* lng  = (const float*)d_in[15];
    const float* lnb  = (const float*)d_in[16];
    const float* inW  = (const float*)d_in[17];
    const float* mcW  = (const float*)d_in[18];
    const float* mcb  = (const float*)d_in[19];
    const float* xpW  = (const float*)d_in[20];
    const float* dtW  = (const float*)d_in[21];
    const float* dtbp = (const float*)d_in[22];
    const float* Alog = (const float*)d_in[23];
    const float* Dp   = (const float*)d_in[24];
    const float* outW = (const float*)d_in[25];
    const float* flW  = (const float*)d_in[26];
    const float* flb  = (const float*)d_in[27];
    const float* fcW  = (const float*)d_in[28];
    const float* fcb  = (const float*)d_in[29];

    float* ws = (float*)d_ws;
    size_t off = 0;
    auto alloc = [&](size_t n) { float* p = ws + off; off += n; return p; };
    float* xe   = alloc((size_t)BLROWS * 128);
    float* xz   = alloc((size_t)BLROWS * 512);   // also 'fused' (head) and mtail (tail)
    float* ub   = alloc((size_t)BLROWS * 256);
    float* dtt  = alloc((size_t)BLROWS * 256);
    float* dbl  = alloc((size_t)BLROWS * 40);
    float* Pb   = alloc((size_t)NBATCH * CHN * 256 * 16);  // reused as pool partials
    float* Sb   = alloc((size_t)NBATCH * CHN * 256 * 16);
    float* h0b  = alloc((size_t)NBATCH * CHN * 256 * 16);
    float* schpack = alloc(640);
    float* fused = xz;
    float* mtail = xz + (size_t)BLROWS * 384;

    off = (off + 3) & ~(size_t)3;
    unsigned short* us = (unsigned short*)(ws + off);
    size_t uo = 0;
    auto ualloc = [&](size_t n) { unsigned short* p = us + uo; uo += n; return p; };
    unsigned short* cch  = ualloc((size_t)BLROWS * 192);  // also lnxh
    unsigned short* ccl  = ualloc((size_t)BLROWS * 192);  // also lnxl
    unsigned short* finh = ualloc((size_t)BLROWS * 256);
    unsigned short* finl = ualloc((size_t)BLROWS * 256);
    unsigned short* ubh  = ualloc((size_t)BLROWS * 256);  // also gbh
    unsigned short* ubl  = ualloc((size_t)BLROWS * 256);  // also gbl
    unsigned short* w192h = ualloc((size_t)192 * 896); unsigned short* w192l = ualloc((size_t)192 * 896);
    unsigned short* cfh = ualloc(128 * 192); unsigned short* cfl = ualloc(128 * 192);
    unsigned short* inh = ualloc((size_t)1536 * 128); unsigned short* inl = ualloc((size_t)1536 * 128);
    unsigned short* xph = ualloc((size_t)3 * 64 * 256); unsigned short* xpl = ualloc((size_t)3 * 64 * 256);
    unsigned short* oth = ualloc((size_t)384 * 256); unsigned short* otl = ualloc((size_t)384 * 256);
    unsigned short* flh = ualloc((size_t)128 * 256); unsigned short* fll = ualloc((size_t)128 * 256);
    unsigned short* lnxh = cch;
    unsigned short* lnxl = ccl;
    unsigned short* gbh  = ubh;
    unsigned short* gbl  = ubl;
    (void)ws_size; (void)in_sizes; (void)n_in; (void)out_size;

    // 0. weights + scale/shift packing
    convw_all<<<(JOB_END + 255) / 256, 256, 0, stream>>>(
        c3W, c5W, c7W, cfW, inW, xpW, outW, flW,
        c3b, c5b, c7b, bn3, bn5, bn7, cfb, bnf,
        w192h, w192l, cfh, cfl, inh, inl, xph, xpl, oth, otl, flh, fll, schpack);

    // 1. embedding + positional encoding
    embed_kernel<<<(BLROWS * 128) / 256, 256, 0, stream>>>(x, embW, embb, xe);

    // 2. CNN branch: unified halo conv-GEMM, then 1x1 fuse
    dim3 gconv(3, 17, NBATCH);
    gemm_conv<<<gconv, 256, 0, stream>>>(xe, w192h, w192l, schpack, schpack + 192, cch, ccl);
    dim3 g17(1, 17, NBATCH);
    gemm_plain<64, 128><<<g17, 256, 0, stream>>>(
        cch, ccl, 192, cfh, cfl, 192, 128, 1,
        schpack + 384, schpack + 512, nullptr, nullptr, 0, finh, finl, 256);

    // 3. three mamba blocks
    for (int i = 0; i < 3; ++i) {
        const float* min_ = (i == 0) ? xe : mtail;

        ln_kernel<<<BLROWS / 4, 256, 0, stream>>>(min_, lng + i * 128, lnb + i * 128, lnxh, lnxl);

        dim3 gin(4, 9, NBATCH);
        gemm_plain<128, 128><<<gin, 256, 0, stream>>>(
            lnxh, lnxl, 128, inh + (size_t)i * 512 * 128, inl + (size_t)i * 512 * 128, 128,
            512, 0, nullptr, nullptr, nullptr, xz, 512, nullptr, nullptr, 0);

        mconv_kernel<<<BLROWS, 256, 0, stream>>>(xz, mcW + i * 256 * 4, mcb + i * 256, ub, ubh, ubl);

        gemm_plain<64, 64><<<g17, 256, 0, stream>>>(
            ubh, ubl, 256, xph + (size_t)i * 64 * 256, xpl + (size_t)i * 64 * 256, 256,
            40, 0, nullptr, nullptr, nullptr, dbl, 40, nullptr, nullptr, 0);

        dtk_kernel<<<BLROWS, 256, 0, stream>>>(dbl, dtW + i * 256 * 8, dtbp + i * 256, dtt);

        scan1_kernel<<<(NBATCH * CHN * 1024) / 256, 256, 0, stream>>>(
            dtt, ub, dbl, Alog + i * 256 * 16, Pb, Sb);
        scan2_kernel<<<(NBATCH * 256 * 16) / 256, 256, 0, stream>>>(Pb, Sb, h0b);
        scan3_kernel<<<(NBATCH * CHN * 1024) / 256, 256, 0, stream>>>(
            dtt, ub, dbl, Alog + i * 256 * 16, h0b, Dp + i * 256, xz, gbh, gbl);

        if (i < 2) {
            gemm_plain<64, 128><<<g17, 256, 0, stream>>>(
                gbh, gbl, 256, oth + (size_t)i * 128 * 256, otl + (size_t)i * 128 * 256, 256,
                128, 0, nullptr, nullptr, nullptr, mtail, 128, nullptr, nullptr, 0);
        } else {
            gemm_plain<64, 128><<<g17, 256, 0, stream>>>(
                gbh, gbl, 256, oth + (size_t)i * 128 * 256, otl + (size_t)i * 128 * 256, 256,
                128, 3, nullptr, nullptr, nullptr, nullptr, 0, finh + 128, finl + 128, 256);
        }
    }

    // 4. fusion linear + relu (fp32 out into 'fused' = xz head)
    gemm_plain<64, 128><<<g17, 256, 0, stream>>>(
        finh, finl, 256, flh, fll, 256, 128, 2,
        nullptr, nullptr, flb, fused, 128, nullptr, nullptr, 0);

    // 5. mean pool + final fc
    pool1_kernel<<<NBATCH * CHN, 128, 0, stream>>>(fused, Pb);
    pool2_kernel<<<NBATCH, 128, 0, stream>>>(Pb, fcW, fcb, (float*)d_out);
}